// Round 17
// baseline (485.019 us; speedup 1.0000x reference)
//
#include <hip/hip_runtime.h>
#include <hip/hip_bf16.h>
#include <math.h>

#define BSZ 4
#define NPT 4096
#define CH  192
#define KNB 16
#define KPH 16              // kept per half (top-16/half provably suffices)
#define KCAND (2 * KPH)     // 32 refine candidates
#define NTOT ((float)(BSZ * NPT))

typedef short short8 __attribute__((ext_vector_type(8)));
typedef float f32x4  __attribute__((ext_vector_type(4)));

__device__ __forceinline__ float gelu_exact(float x){
    return 0.5f * x * (1.0f + erff(x * 0.70710678118654752440f));
}
__device__ __forceinline__ unsigned int umin_(unsigned int a, unsigned int b){ return a < b ? a : b; }
__device__ __forceinline__ unsigned int umax_(unsigned int a, unsigned int b){ return a < b ? b : a; }
__device__ __forceinline__ unsigned short bf16rnd(float v){
    unsigned int bits = __builtin_bit_cast(unsigned int, v);
    return (unsigned short)((bits + 0x7fff + ((bits >> 16) & 1)) >> 16);
}

// ---------------- fc1 with f64 accumulation -> f64 t1 -------------------------------------------
__global__ __launch_bounds__(256) void k_fc1_f64(
    const float* __restrict__ in, const float* __restrict__ W, double* __restrict__ outd)
{
    constexpr int OT = 8, NT = 4;
    __shared__ float wtT[CH][OT];
    const int tid = threadIdx.x;
    const int o0  = blockIdx.y * OT;
    const int b   = blockIdx.z;
    const int n   = blockIdx.x * (256 * NT) + tid * NT;

    for (int lin = tid; lin < CH * OT; lin += 256){
        int c = lin >> 3, o = lin & 7;
        wtT[c][o] = W[(size_t)(o0 + o) * CH + c];
    }
    __syncthreads();

    double acc[OT][NT] = {};
    const float* ip = in + (size_t)b * CH * NPT + n;
    for (int c = 0; c < CH; ++c){
        float4 x4 = *reinterpret_cast<const float4*>(ip + (size_t)c * NPT);
        double xv[NT] = {x4.x, x4.y, x4.z, x4.w};
        float4 w0 = *reinterpret_cast<const float4*>(&wtT[c][0]);
        float4 w1 = *reinterpret_cast<const float4*>(&wtT[c][4]);
        double wv[OT] = {w0.x, w0.y, w0.z, w0.w, w1.x, w1.y, w1.z, w1.w};
        #pragma unroll
        for (int oo = 0; oo < OT; ++oo)
            #pragma unroll
            for (int j = 0; j < NT; ++j)
                acc[oo][j] = fma(wv[oo], xv[j], acc[oo][j]);
    }

    #pragma unroll
    for (int oo = 0; oo < OT; ++oo){
        size_t off = ((size_t)b * CH + o0 + oo) * NPT + n;
        #pragma unroll
        for (int j = 0; j < 4; ++j) outd[off + j] = acc[oo][j];
    }
}

// ---------------- f64 BN0 stats: fp32 scale/shift + f64 scale -----------------------------------
__global__ __launch_bounds__(256) void k_stats_f64(
    const double* __restrict__ t, const float* __restrict__ gamma,
    const float* __restrict__ beta, float* __restrict__ scale,
    float* __restrict__ shift, double* __restrict__ scd)
{
    const int c = blockIdx.x, tid = threadIdx.x;
    double s = 0., s2 = 0.;
    for (int b = 0; b < BSZ; ++b){
        const double* p = t + ((size_t)b * CH + c) * NPT;
        for (int n = tid; n < NPT; n += 256){ double v = p[n]; s += v; s2 += v * v; }
    }
    __shared__ double rs[256], rs2[256];
    rs[tid] = s; rs2[tid] = s2; __syncthreads();
    for (int off = 128; off; off >>= 1){
        if (tid < off){ rs[tid] += rs[tid + off]; rs2[tid] += rs2[tid + off]; }
        __syncthreads();
    }
    if (tid == 0){
        const double invn = 1.0 / (BSZ * NPT);
        double mean = rs[0] * invn;
        double var  = rs2[0] * invn - mean * mean;
        double rstd = 1.0 / sqrt(var + 1e-5);
        double s_   = rstd * (double)gamma[c];
        scale[c] = (float)s_;
        shift[c] = (float)((double)beta[c] - mean * s_);
        scd[c]   = s_;
    }
}

// ---------------- fused: transpose+scale -> featT(f64), feat32, featP (MFMA-fragment bf16), sqv -
__global__ void k_feat(
    const double* __restrict__ t1d, const double* __restrict__ scd,
    double* __restrict__ featT, float* __restrict__ feat32,
    unsigned short* __restrict__ featP, float* __restrict__ sqv)
{
    __shared__ double tile[32][33];
    __shared__ float sqp[32][33];
    const int n0 = blockIdx.x * 32, b = blockIdx.y;
    const int tx = threadIdx.x, ty = threadIdx.y;
    const int tid = ty * 32 + tx;
    float part[4] = {0.f, 0.f, 0.f, 0.f};
    unsigned short* fpb = featP + (size_t)b * NPT * CH;

    for (int cc = 0; cc < CH / 32; ++cc){
        const int cbase = cc * 32;
        #pragma unroll
        for (int r = 0; r < 32; r += 8){
            int c = cbase + ty + r;
            tile[ty + r][tx] = t1d[((size_t)b * CH + c) * NPT + n0 + tx] * scd[c];
        }
        __syncthreads();
        #pragma unroll
        for (int r = 0; r < 32; r += 8){
            int n = n0 + ty + r;
            int c = cbase + tx;
            double v = tile[tx][ty + r];
            size_t o = ((size_t)b * NPT + n) * CH + c;
            featT[o] = v;
            float f = (float)v;
            feat32[o] = f;
            part[r >> 3] = fmaf(f, f, part[r >> 3]);
        }
        if (tid < 128){
            const int t_ = tid >> 6;
            const int l  = tid & 63;
            const int r_ = l & 15, g_ = l >> 4;
            const int nl = t_ * 16 + r_;
            short8 pk;
            #pragma unroll
            for (int e = 0; e < 8; ++e)
                pk[e] = (short)bf16rnd((float)tile[g_ * 8 + e][nl]);
            const int tP = blockIdx.x * 2 + t_;
            *reinterpret_cast<short8*>(fpb + (size_t)(tP * 6 + cc) * 512 + l * 8) = pk;
        }
        __syncthreads();
    }
    #pragma unroll
    for (int j = 0; j < 4; ++j) sqp[ty + 8 * j][tx] = part[j];
    __syncthreads();
    if (ty == 0){
        float s = 0.f;
        #pragma unroll 8
        for (int k = 0; k < 32; ++k) s += sqp[tx][k];
        sqv[b * NPT + n0 + tx] = s;
    }
}

// ---------------- MFMA kNN prefilter v10: lane-contiguous fragment loads ------------------------
__global__ __launch_bounds__(512, 4) void k_knn_mfma(
    const unsigned short* __restrict__ featP, const float* __restrict__ sqv,
    int* __restrict__ idxh)
{
    __shared__ unsigned int mlist[8][16][17];
    const int tid  = threadIdx.x;
    const int wv   = tid >> 6;
    const int lane = tid & 63;
    const int r = lane & 15, g = lane >> 4;
    const int b    = blockIdx.y;
    const int qt   = blockIdx.x >> 1;
    const int half = blockIdx.x & 1;
    const int qs = wv >> 1, mq = wv & 1;
    const int tq   = qt * 4 + qs;
    const int tm0  = half * 128 + mq * 64;
    const unsigned short* fp = featP + (size_t)b * NPT * CH;

    short8 bq0, bq1, bq2, bq3, bq4, bq5;
    {
        const unsigned short* qp = fp + (size_t)tq * 3072 + lane * 8;
        bq0 = *reinterpret_cast<const short8*>(qp);
        bq1 = *reinterpret_cast<const short8*>(qp + 512);
        bq2 = *reinterpret_cast<const short8*>(qp + 1024);
        bq3 = *reinterpret_cast<const short8*>(qp + 1536);
        bq4 = *reinterpret_cast<const short8*>(qp + 2048);
        bq5 = *reinterpret_cast<const short8*>(qp + 2560);
    }

    unsigned int Q[16];
    #pragma unroll
    for (int e = 0; e < 16; ++e) Q[e] = 0xFFFFFFFFu;

    const float* sq = sqv + b * NPT;
    const unsigned short* pa = fp + (size_t)tm0 * 3072 + lane * 8;

    for (int it = 0; it < 64; ++it){
        const unsigned short* p = pa + (size_t)it * 3072;
        short8 a0 = *reinterpret_cast<const short8*>(p);
        short8 a1 = *reinterpret_cast<const short8*>(p + 512);
        short8 a2 = *reinterpret_cast<const short8*>(p + 1024);
        short8 a3 = *reinterpret_cast<const short8*>(p + 1536);
        short8 a4 = *reinterpret_cast<const short8*>(p + 2048);
        short8 a5 = *reinterpret_cast<const short8*>(p + 2560);
        const int tm = tm0 + it;
        float4 s4 = *reinterpret_cast<const float4*>(sq + tm * 16 + 4 * g);

        f32x4 acc = {0.f, 0.f, 0.f, 0.f};
        acc = __builtin_amdgcn_mfma_f32_16x16x32_bf16(a0, bq0, acc, 0, 0, 0);
        acc = __builtin_amdgcn_mfma_f32_16x16x32_bf16(a1, bq1, acc, 0, 0, 0);
        acc = __builtin_amdgcn_mfma_f32_16x16x32_bf16(a2, bq2, acc, 0, 0, 0);
        acc = __builtin_amdgcn_mfma_f32_16x16x32_bf16(a3, bq3, acc, 0, 0, 0);
        acc = __builtin_amdgcn_mfma_f32_16x16x32_bf16(a4, bq4, acc, 0, 0, 0);
        acc = __builtin_amdgcn_mfma_f32_16x16x32_bf16(a5, bq5, acc, 0, 0, 0);

        const int m0 = tm * 16 + 4 * g;
        float sa[4] = {s4.x, s4.y, s4.z, s4.w};
        #pragma unroll
        for (int u = 0; u < 4; ++u){
            float d = fmaf(-2.0f, acc[u], sa[u]);
            int bb = __builtin_bit_cast(int, d);
            unsigned int uu = (unsigned int)(bb ^ ((bb >> 31) | 0x80000000));
            unsigned int k  = (uu & 0xFFFFF000u) | (unsigned int)(m0 + u);
            #pragma unroll
            for (int e = 0; e < 16; ++e){
                unsigned int qe = Q[e];
                Q[e] = umin_(k, qe);
                k    = umax_(k, qe);
            }
        }
    }

    #pragma unroll 1
    for (int rd = 0; rd < 16; ++rd){
        unsigned int v = Q[0];
        v = umin_(v, (unsigned int)__shfl_xor((int)v, 16));
        v = umin_(v, (unsigned int)__shfl_xor((int)v, 32));
        bool win = (Q[0] == v);
        if (win){
            #pragma unroll
            for (int e = 0; e < 15; ++e) Q[e] = Q[e + 1];
            Q[15] = 0xFFFFFFFFu;
        }
        if (g == 0) mlist[wv][r][rd] = v;
    }
    if (g == 0) mlist[wv][r][16] = 0xFFFFFFFFu;
    __syncthreads();

    if (tid < 64){
        const int qsub = tid >> 4, rr = tid & 15;
        int i0 = 0, i1 = 0;
        int* op = idxh + ((size_t)(b * NPT + qt * 64 + qsub * 16 + rr) * 2 + half) * KPH;
        for (int rd = 0; rd < KPH; ++rd){
            unsigned int k0 = mlist[qsub * 2][rr][i0];
            unsigned int k1 = mlist[qsub * 2 + 1][rr][i1];
            unsigned int mm = umin_(k0, k1);
            op[rd] = (int)(mm & 0xFFFu);
            i0 += (k0 == mm); i1 += (k1 == mm);
        }
    }
}

// ---------------- fused refine + gather: top-16 (certified) then L2-hot max-rel aggregate -------
// block = 32 queries, 256 thr. Phase A: 8 lane-groups of 32, each refines 4 queries sequentially
// (chunked-ILP fp32 + certified f64 fallback), top-16 -> LDS. Phase B: gather with neighbor rows
// L2/L1-hot from phase A; LDS-transposed channel-major hcat write (full 384 rows).
__global__ __launch_bounds__(256) void k_refgather(
    const float* __restrict__ feat32, const double* __restrict__ featT,
    const int* __restrict__ idxh, const float* __restrict__ sh0,
    float* __restrict__ hcat)
{
    __shared__ float lt[384 * 33];                 // 50.7 KB
    __shared__ int   topk[32][KNB];                // 2 KB
    const int tid = threadIdx.x;
    const int n0  = blockIdx.x * 32;
    const int b   = blockIdx.y;
    const int sl  = tid & 31;

    // ---- phase A: refine 4 queries per 32-lane group ----
    for (int qq = 0; qq < 4; ++qq){
        const int ql = (tid >> 5) * 4 + qq;
        const int q  = n0 + ql;
        const int* cl = idxh + ((size_t)b * NPT + q) * KCAND;
        const float* qv = feat32 + ((size_t)b * NPT + q) * CH;
        float qr[6];
        #pragma unroll
        for (int j = 0; j < 6; ++j) qr[j] = qv[sl + 32 * j];

        float myd = INFINITY; int mym = 0x7fffffff;
        #pragma unroll
        for (int t0 = 0; t0 < KCAND; t0 += 8){
            float pd[8]; int cm[8];
            #pragma unroll
            for (int j = 0; j < 8; ++j){
                int m = cl[t0 + j];
                cm[j] = m;
                const float* cv = feat32 + ((size_t)b * NPT + m) * CH;
                float d = 0.f;
                #pragma unroll
                for (int e = 0; e < 6; ++e){
                    float dv = cv[sl + 32 * e] - qr[e];
                    d = fmaf(dv, dv, d);
                }
                pd[j] = d;
            }
            #pragma unroll
            for (int j = 0; j < 8; ++j){
                float d = pd[j];
                #pragma unroll
                for (int off = 16; off; off >>= 1) d += __shfl_xor(d, off, 32);
                if (sl == t0 + j){ myd = d; mym = cm[j]; }
            }
        }

        float d16 = 0.f;
        for (int r = 0; r < KNB; ++r){
            float bv = myd; int bi = mym;
            #pragma unroll
            for (int off = 16; off; off >>= 1){
                float ov = __shfl_xor(bv, off, 32);
                int   oi = __shfl_xor(bi, off, 32);
                if (ov < bv || (ov == bv && oi < bi)){ bv = ov; bi = oi; }
            }
            if (sl == 0) topk[ql][r] = bi;
            if (mym == bi){ myd = INFINITY; mym = 0x7fffffff; }
            d16 = bv;
        }
        float b17 = myd;
        #pragma unroll
        for (int off = 16; off; off >>= 1) b17 = fminf(b17, __shfl_xor(b17, off, 32));
        int flag = (b17 - d16 < 1e-3f + 2e-4f * d16) ? 1 : 0;
        flag = __shfl(flag, 0, 32);
        if (flag){
            const double* qvd = featT + ((size_t)b * NPT + q) * CH;
            double qrd[6];
            #pragma unroll
            for (int j = 0; j < 6; ++j) qrd[j] = qvd[sl + 32 * j];
            double mydd = INFINITY; int mymd = 0x7fffffff;
            for (int t = 0; t < KCAND; ++t){
                int m = cl[t];
                const double* cv = featT + ((size_t)b * NPT + m) * CH;
                double d = 0.;
                #pragma unroll
                for (int e = 0; e < 6; ++e){
                    double dv = cv[sl + 32 * e] - qrd[e];
                    d = fma(dv, dv, d);
                }
                #pragma unroll
                for (int off = 16; off; off >>= 1) d += __shfl_xor(d, off, 32);
                if (sl == t){ mydd = d; mymd = m; }
            }
            for (int r = 0; r < KNB; ++r){
                double bv = mydd; int bi = mymd;
                #pragma unroll
                for (int off = 16; off; off >>= 1){
                    double ov = __shfl_xor(bv, off, 32);
                    int    oi = __shfl_xor(bi, off, 32);
                    if (ov < bv || (ov == bv && oi < bi)){ bv = ov; bi = oi; }
                }
                if (sl == 0) topk[ql][r] = bi;
                if (mymd == bi){ mydd = INFINITY; mymd = 0x7fffffff; }
            }
        }
    }
    __syncthreads();

    // ---- phase B: gather (rows L2-hot), full 192 channels, LDS transpose ----
    {
        const int nl = tid >> 3, sub = tid & 7;     // 32 n x 8 subs, 24 ch each
        const int n  = n0 + nl;
        const float* fbase = feat32 + (size_t)b * NPT * CH;
        const float* qr = fbase + (size_t)n * CH;

        float4 qv[6], mx[6];
        #pragma unroll
        for (int j = 0; j < 6; ++j){
            qv[j] = *reinterpret_cast<const float4*>(qr + (sub + 8 * j) * 4);
            mx[j] = make_float4(-INFINITY, -INFINITY, -INFINITY, -INFINITY);
        }

        #pragma unroll 4
        for (int k = 0; k < KNB; ++k){
            const float* cr = fbase + (size_t)topk[nl][k] * CH;
            #pragma unroll
            for (int j = 0; j < 6; ++j){
                float4 v = *reinterpret_cast<const float4*>(cr + (sub + 8 * j) * 4);
                mx[j].x = fmaxf(mx[j].x, v.x - qv[j].x);
                mx[j].y = fmaxf(mx[j].y, v.y - qv[j].y);
                mx[j].z = fmaxf(mx[j].z, v.z - qv[j].z);
                mx[j].w = fmaxf(mx[j].w, v.w - qv[j].w);
            }
        }

        #pragma unroll
        for (int j = 0; j < 6; ++j){
            const int cb = (sub + 8 * j) * 4;       // local c base (0..191)
            float4 s4 = *reinterpret_cast<const float4*>(sh0 + cb);
            float fi[4] = {qv[j].x + s4.x, qv[j].y + s4.y, qv[j].z + s4.z, qv[j].w + s4.w};
            float mm[4] = {mx[j].x, mx[j].y, mx[j].z, mx[j].w};
            #pragma unroll
            for (int e = 0; e < 4; ++e){
                int cl = cb + e;
                lt[(2 * cl) * 33 + nl]     = fi[e];
                lt[(2 * cl + 1) * 33 + nl] = mm[e];
            }
        }
    }
    __syncthreads();

    {
        const int rsub = tid >> 5;       // 0..7
        const int ni   = tid & 31;
        for (int r0 = 0; r0 < 384; r0 += 8){
            int row = r0 + rsub;
            hcat[((size_t)b * 2 * CH + row) * NPT + n0 + ni] = lt[row * 33 + ni];
        }
    }
}

// ---------------- mr-conv GEMM (K=384) + bias, with fused BN1-stat atomics ----------------------
__global__ __launch_bounds__(256) void k_gemm_mr(
    const float* __restrict__ in, const float* __restrict__ W, const float* __restrict__ bias,
    float* __restrict__ out, float* __restrict__ s1sum, float* __restrict__ s1sq)
{
    constexpr int KDIM = 2 * CH, OT = 8, NT = 4;
    __shared__ float wtT[KDIM][OT];
    __shared__ float redS[4][8], redQ[4][8];
    const int tid = threadIdx.x;
    const int o0  = blockIdx.y * OT;
    const int b   = blockIdx.z;
    const int n   = blockIdx.x * (256 * NT) + tid * NT;

    for (int lin = tid; lin < KDIM * OT; lin += 256){
        int c = lin >> 3, o = lin & 7;
        wtT[c][o] = W[(size_t)(o0 + o) * KDIM + c];
    }
    __syncthreads();

    float acc[OT][NT] = {};
    const float* ip = in + (size_t)b * KDIM * NPT + n;
    #pragma unroll 2
    for (int c = 0; c < KDIM; ++c){
        float4 x4 = *reinterpret_cast<const float4*>(ip + (size_t)c * NPT);
        float xv[NT] = {x4.x, x4.y, x4.z, x4.w};
        float4 w0 = *reinterpret_cast<const float4*>(&wtT[c][0]);
        float4 w1 = *reinterpret_cast<const float4*>(&wtT[c][4]);
        float wv[OT] = {w0.x, w0.y, w0.z, w0.w, w1.x, w1.y, w1.z, w1.w};
        #pragma unroll
        for (int oo = 0; oo < OT; ++oo)
            #pragma unroll
            for (int j = 0; j < NT; ++j)
                acc[oo][j] = fmaf(wv[oo], xv[j], acc[oo][j]);
    }

    float ps[OT], pq[OT];
    #pragma unroll
    for (int oo = 0; oo < OT; ++oo){
        size_t off = ((size_t)b * CH + o0 + oo) * NPT + n;
        float add = bias[o0 + oo];
        float vals[4];
        float s = 0.f, q = 0.f;
        #pragma unroll
        for (int j = 0; j < 4; ++j){
            vals[j] = acc[oo][j] + add;
            s += vals[j];
            q = fmaf(vals[j], vals[j], q);
        }
        ps[oo] = s; pq[oo] = q;
        float4 o4; o4.x = vals[0]; o4.y = vals[1]; o4.z = vals[2]; o4.w = vals[3];
        *reinterpret_cast<float4*>(out + off) = o4;
    }

    #pragma unroll
    for (int oo = 0; oo < OT; ++oo){
        #pragma unroll
        for (int off = 32; off; off >>= 1){
            ps[oo] += __shfl_xor(ps[oo], off);
            pq[oo] += __shfl_xor(pq[oo], off);
        }
    }
    const int wv = tid >> 6, lane = tid & 63;
    if (lane == 0){
        #pragma unroll
        for (int oo = 0; oo < OT; ++oo){ redS[wv][oo] = ps[oo]; redQ[wv][oo] = pq[oo]; }
    }
    __syncthreads();
    if (tid < 8){
        float s = redS[0][tid] + redS[1][tid] + redS[2][tid] + redS[3][tid];
        float q = redQ[0][tid] + redQ[1][tid] + redQ[2][tid] + redQ[3][tid];
        atomicAdd(&s1sum[o0 + tid], s);
        atomicAdd(&s1sq[o0 + tid], q);
    }
}

// ---------------- u = gelu(gelu(BN1(t2))), BN1 from sums; fused BN2-stat atomics ----------------
__global__ __launch_bounds__(256) void k_u(
    const float* __restrict__ in, const float* __restrict__ s1sum, const float* __restrict__ s1sq,
    const float* __restrict__ gm, const float* __restrict__ bm,
    float* __restrict__ out, float* __restrict__ s2sum, float* __restrict__ s2sq)
{
    __shared__ float redS[4], redQ[4];
    const int c = blockIdx.y, b = blockIdx.z;
    const int n = (blockIdx.x * 256 + threadIdx.x) * 4;
    const float invn = 1.0f / NTOT;
    float mean = s1sum[c] * invn;
    float var  = s1sq[c] * invn - mean * mean;
    float rstd = rsqrtf(var + 1e-5f);
    float s = rstd * gm[c], t = bm[c] - mean * s;

    size_t i = ((size_t)b * CH + c) * NPT + n;
    float4 v = *reinterpret_cast<const float4*>(in + i);
    float4 o;
    o.x = gelu_exact(gelu_exact(fmaf(v.x, s, t)));
    o.y = gelu_exact(gelu_exact(fmaf(v.y, s, t)));
    o.z = gelu_exact(gelu_exact(fmaf(v.z, s, t)));
    o.w = gelu_exact(gelu_exact(fmaf(v.w, s, t)));
    *reinterpret_cast<float4*>(out + i) = o;

    float ps = o.x + o.y + o.z + o.w;
    float pq = fmaf(o.x, o.x, fmaf(o.y, o.y, fmaf(o.z, o.z, o.w * o.w)));
    #pragma unroll
    for (int off = 32; off; off >>= 1){
        ps += __shfl_xor(ps, off);
        pq += __shfl_xor(pq, off);
    }
    const int wv = threadIdx.x >> 6, lane = threadIdx.x & 63;
    if (lane == 0){ redS[wv] = ps; redQ[wv] = pq; }
    __syncthreads();
    if (threadIdx.x == 0){
        atomicAdd(&s2sum[c], redS[0] + redS[1] + redS[2] + redS[3]);
        atomicAdd(&s2sq[c],  redQ[0] + redQ[1] + redQ[2] + redQ[3]);
    }
}

// ---------------- fc2 GEMM with BN2 (from sums) folded into input + residual --------------------
__global__ __launch_bounds__(256) void k_gemm_fc2(
    const float* __restrict__ in, const float* __restrict__ W,
    const float* __restrict__ s2sum, const float* __restrict__ s2sq,
    const float* __restrict__ g1, const float* __restrict__ b1,
    const float* __restrict__ resid, float* __restrict__ out)
{
    constexpr int KDIM = CH, OT = 8, NT = 4;
    __shared__ float wtT[KDIM][OT];
    __shared__ float scl[KDIM], shl[KDIM];
    const int tid = threadIdx.x;
    const int o0  = blockIdx.y * OT;
    const int b   = blockIdx.z;
    const int n   = blockIdx.x * (256 * NT) + tid * NT;

    for (int lin = tid; lin < KDIM * OT; lin += 256){
        int c = lin >> 3, o = lin & 7;
        wtT[c][o] = W[(size_t)(o0 + o) * KDIM + c];
    }
    const float invn = 1.0f / NTOT;
    for (int c = tid; c < KDIM; c += 256){
        float mean = s2sum[c] * invn;
        float var  = s2sq[c] * invn - mean * mean;
        float rstd = rsqrtf(var + 1e-5f);
        float s = rstd * g1[c];
        scl[c] = s;
        shl[c] = b1[c] - mean * s;
    }
    __syncthreads();

    float acc[OT][NT] = {};
    const float* ip = in + (size_t)b * KDIM * NPT + n;
    #pragma unroll 2
    for (int c = 0; c < KDIM; ++c){
        float4 x4 = *reinterpret_cast<const float4*>(ip + (size_t)c * NPT);
        float xv[NT];
        xv[0] = fmaf(x4.x, scl[c], shl[c]);
        xv[1] = fmaf(x4.y, scl[c], shl[c]);
        xv[2] = fmaf(x4.z, scl[c], shl[c]);
        xv[3] = fmaf(x4.w, scl[c], shl[c]);
        float4 w0 = *reinterpret_cast<const float4*>(&wtT[c][0]);
        float4 w1 = *reinterpret_cast<const float4*>(&wtT[c][4]);
        float wv[OT] = {w0.x, w0.y, w0.z, w0.w, w1.x, w1.y, w1.z, w1.w};
        #pragma unroll
        for (int oo = 0; oo < OT; ++oo)
            #pragma unroll
            for (int j = 0; j < NT; ++j)
                acc[oo][j] = fmaf(wv[oo], xv[j], acc[oo][j]);
    }

    #pragma unroll
    for (int oo = 0; oo < OT; ++oo){
        size_t off = ((size_t)b * CH + o0 + oo) * NPT + n;
        float4 r4 = *reinterpret_cast<const float4*>(resid + off);
        float4 o4;
        o4.x = acc[oo][0] + r4.x; o4.y = acc[oo][1] + r4.y;
        o4.z = acc[oo][2] + r4.z; o4.w = acc[oo][3] + r4.w;
        *reinterpret_cast<float4*>(out + off) = o4;
    }
}

extern "C" void kernel_launch(void* const* d_in, const int* in_sizes, int n_in,
                              void* d_out, int out_size, void* d_ws, size_t ws_size,
                              hipStream_t stream)
{
    const float* x    = (const float*)d_in[0];
    const float* w1   = (const float*)d_in[1];
    const float* w2   = (const float*)d_in[2];
    const float* wmr  = (const float*)d_in[3];
    const float* bmr  = (const float*)d_in[4];
    const float* g0   = (const float*)d_in[5];
    const float* b0   = (const float*)d_in[6];
    const float* gm   = (const float*)d_in[7];
    const float* bm   = (const float*)d_in[8];
    const float* g1   = (const float*)d_in[9];
    const float* b1   = (const float*)d_in[10];
    float* outp = (float*)d_out;

    const size_t BCN = (size_t)BSZ * CH * NPT;
    float*  A      = (float*)d_ws;                       // BCN f32: t2
    float*  Bb     = A + BCN;                            // BCN f32: featP (bf16) -> u
    unsigned short* featP = (unsigned short*)Bb;
    float*  Cc     = Bb + BCN;                           // 2*BCN f32: t1d (f64) -> hcat
    double* t1d    = (double*)Cc;
    double* featT  = (double*)(Cc + 2 * BCN);            // BCN f64
    float*  feat32 = (float*)(featT + BCN);              // BCN f32
    float*  sqv    = feat32 + BCN;                       // B*N
    int*    idxh   = (int*)(sqv + (size_t)BSZ * NPT);    // B*N*32
    float*  bnacc  = (float*)(idxh + (size_t)BSZ * NPT * KCAND);  // 4*CH f32
    float *s1sum = bnacc, *s1sq = bnacc + CH, *s2sum = bnacc + 2 * CH, *s2sq = bnacc + 3 * CH;
    double* scd    = (double*)(bnacc + 4 * CH);
    float*  scb    = (float*)(scd + CH);
    float *sc0 = scb, *sh0 = scb + CH;

    dim3 gg(NPT / 1024, CH / 8, BSZ);
    dim3 ge(NPT / 1024, CH, BSZ);

    hipMemsetAsync(bnacc, 0, 4 * CH * sizeof(float), stream);
    // fc1 (f64 accumulate)
    k_fc1_f64<<<gg, 256, 0, stream>>>(x, w1, t1d);
    // BN0 stats in f64
    k_stats_f64<<<CH, 256, 0, stream>>>(t1d, g0, b0, sc0, sh0, scd);
    // fused transpose/scale -> featT + feat32 + featP(fragment layout) + sqv
    k_feat<<<dim3(NPT / 32, BSZ), dim3(32, 8), 0, stream>>>(t1d, scd, featT, feat32, featP, sqv);
    // kNN prefilter (lane-contiguous fragment loads, top-16/half)
    k_knn_mfma<<<dim3(2 * NPT / 64, BSZ), 512, 0, stream>>>(featP, sqv, idxh);
    // fused refine + gather (writes hcat over dead t1d)
    k_refgather<<<dim3(NPT / 32, BSZ), 256, 0, stream>>>(feat32, featT, idxh, sh0, Cc);
    // mr conv + bias + BN1-stat atomics
    k_gemm_mr<<<gg, 256, 0, stream>>>(Cc, wmr, bmr, A, s1sum, s1sq);
    // u = gelu(gelu(BN1(t2))) + BN2-stat atomics
    k_u<<<ge, 256, 0, stream>>>(A, s1sum, s1sq, gm, bm, Bb, s2sum, s2sq);
    // fc2 with BN2 folded + residual
    k_gemm_fc2<<<gg, 256, 0, stream>>>(Bb, w2, s2sum, s2sq, g1, b1, x, outp);
}

// Round 18
// 424.669 us; speedup vs baseline: 1.1421x; 1.1421x over previous
//
#include <hip/hip_runtime.h>
#include <hip/hip_bf16.h>
#include <math.h>

#define BSZ 4
#define NPT 4096
#define CH  192
#define KNB 16
#define KPH 16              // kept per half (top-16/half provably suffices)
#define KCAND (2 * KPH)     // 32 refine candidates
#define NTOT ((float)(BSZ * NPT))

typedef short short8 __attribute__((ext_vector_type(8)));
typedef float f32x4  __attribute__((ext_vector_type(4)));

__device__ __forceinline__ float gelu_exact(float x){
    return 0.5f * x * (1.0f + erff(x * 0.70710678118654752440f));
}
__device__ __forceinline__ unsigned int umin_(unsigned int a, unsigned int b){ return a < b ? a : b; }
__device__ __forceinline__ unsigned int umax_(unsigned int a, unsigned int b){ return a < b ? b : a; }
__device__ __forceinline__ unsigned int umed3_(unsigned int a, unsigned int b, unsigned int c){
    unsigned int r;
    asm("v_med3_u32 %0, %1, %2, %3" : "=v"(r) : "v"(a), "v"(b), "v"(c));
    return r;
}
__device__ __forceinline__ unsigned short bf16rnd(float v){
    unsigned int bits = __builtin_bit_cast(unsigned int, v);
    return (unsigned short)((bits + 0x7fff + ((bits >> 16) & 1)) >> 16);
}

// ---------------- fc1 with f64 accumulation -> f64 t1 -------------------------------------------
__global__ __launch_bounds__(256) void k_fc1_f64(
    const float* __restrict__ in, const float* __restrict__ W, double* __restrict__ outd)
{
    constexpr int OT = 8, NT = 4;
    __shared__ float wtT[CH][OT];
    const int tid = threadIdx.x;
    const int o0  = blockIdx.y * OT;
    const int b   = blockIdx.z;
    const int n   = blockIdx.x * (256 * NT) + tid * NT;

    for (int lin = tid; lin < CH * OT; lin += 256){
        int c = lin >> 3, o = lin & 7;
        wtT[c][o] = W[(size_t)(o0 + o) * CH + c];
    }
    __syncthreads();

    double acc[OT][NT] = {};
    const float* ip = in + (size_t)b * CH * NPT + n;
    for (int c = 0; c < CH; ++c){
        float4 x4 = *reinterpret_cast<const float4*>(ip + (size_t)c * NPT);
        double xv[NT] = {x4.x, x4.y, x4.z, x4.w};
        float4 w0 = *reinterpret_cast<const float4*>(&wtT[c][0]);
        float4 w1 = *reinterpret_cast<const float4*>(&wtT[c][4]);
        double wv[OT] = {w0.x, w0.y, w0.z, w0.w, w1.x, w1.y, w1.z, w1.w};
        #pragma unroll
        for (int oo = 0; oo < OT; ++oo)
            #pragma unroll
            for (int j = 0; j < NT; ++j)
                acc[oo][j] = fma(wv[oo], xv[j], acc[oo][j]);
    }

    #pragma unroll
    for (int oo = 0; oo < OT; ++oo){
        size_t off = ((size_t)b * CH + o0 + oo) * NPT + n;
        #pragma unroll
        for (int j = 0; j < 4; ++j) outd[off + j] = acc[oo][j];
    }
}

// ---------------- f64 BN0 stats: fp32 scale/shift + f64 scale -----------------------------------
__global__ __launch_bounds__(256) void k_stats_f64(
    const double* __restrict__ t, const float* __restrict__ gamma,
    const float* __restrict__ beta, float* __restrict__ scale,
    float* __restrict__ shift, double* __restrict__ scd)
{
    const int c = blockIdx.x, tid = threadIdx.x;
    double s = 0., s2 = 0.;
    for (int b = 0; b < BSZ; ++b){
        const double* p = t + ((size_t)b * CH + c) * NPT;
        for (int n = tid; n < NPT; n += 256){ double v = p[n]; s += v; s2 += v * v; }
    }
    __shared__ double rs[256], rs2[256];
    rs[tid] = s; rs2[tid] = s2; __syncthreads();
    for (int off = 128; off; off >>= 1){
        if (tid < off){ rs[tid] += rs[tid + off]; rs2[tid] += rs2[tid + off]; }
        __syncthreads();
    }
    if (tid == 0){
        const double invn = 1.0 / (BSZ * NPT);
        double mean = rs[0] * invn;
        double var  = rs2[0] * invn - mean * mean;
        double rstd = 1.0 / sqrt(var + 1e-5);
        double s_   = rstd * (double)gamma[c];
        scale[c] = (float)s_;
        shift[c] = (float)((double)beta[c] - mean * s_);
        scd[c]   = s_;
    }
}

// ---------------- fused: transpose+scale -> featT(f64), feat32, featP (MFMA-fragment bf16), sqv -
__global__ void k_feat(
    const double* __restrict__ t1d, const double* __restrict__ scd,
    double* __restrict__ featT, float* __restrict__ feat32,
    unsigned short* __restrict__ featP, float* __restrict__ sqv)
{
    __shared__ double tile[32][33];
    __shared__ float sqp[32][33];
    const int n0 = blockIdx.x * 32, b = blockIdx.y;
    const int tx = threadIdx.x, ty = threadIdx.y;
    const int tid = ty * 32 + tx;
    float part[4] = {0.f, 0.f, 0.f, 0.f};
    unsigned short* fpb = featP + (size_t)b * NPT * CH;

    for (int cc = 0; cc < CH / 32; ++cc){
        const int cbase = cc * 32;
        #pragma unroll
        for (int r = 0; r < 32; r += 8){
            int c = cbase + ty + r;
            tile[ty + r][tx] = t1d[((size_t)b * CH + c) * NPT + n0 + tx] * scd[c];
        }
        __syncthreads();
        #pragma unroll
        for (int r = 0; r < 32; r += 8){
            int n = n0 + ty + r;
            int c = cbase + tx;
            double v = tile[tx][ty + r];
            size_t o = ((size_t)b * NPT + n) * CH + c;
            featT[o] = v;
            float f = (float)v;
            feat32[o] = f;
            part[r >> 3] = fmaf(f, f, part[r >> 3]);
        }
        if (tid < 128){
            const int t_ = tid >> 6;
            const int l  = tid & 63;
            const int r_ = l & 15, g_ = l >> 4;
            const int nl = t_ * 16 + r_;
            short8 pk;
            #pragma unroll
            for (int e = 0; e < 8; ++e)
                pk[e] = (short)bf16rnd((float)tile[g_ * 8 + e][nl]);
            const int tP = blockIdx.x * 2 + t_;
            *reinterpret_cast<short8*>(fpb + (size_t)(tP * 6 + cc) * 512 + l * 8) = pk;
        }
        __syncthreads();
    }
    #pragma unroll
    for (int j = 0; j < 4; ++j) sqp[ty + 8 * j][tx] = part[j];
    __syncthreads();
    if (ty == 0){
        float s = 0.f;
        #pragma unroll 8
        for (int k = 0; k < 32; ++k) s += sqp[tx][k];
        sqv[b * NPT + n0 + tx] = s;
    }
}

// ---------------- MFMA kNN prefilter v11: fragment loads + med3 pair-chain insert ---------------
// grid (2*NPT/64, BSZ), 512 thr (8 waves). wave wv: q-sub (wv>>1, 16 q), m-quarter (wv&1).
// key = clamped-nonneg f32 distance bits (top 20) | index (12 bits). True distances >= 0; bf16
// noise can make near-zero distances negative -> clamp to 0 keeps them top-ranked; the exact
// refine re-ranks candidates, so only SET membership matters. Insert: med3 pair-chain,
// 3 ops / 2 slots (25% fewer VALU ops than min/max bubble; carry chain 8 deep).
__global__ __launch_bounds__(512, 4) void k_knn_mfma(
    const unsigned short* __restrict__ featP, const float* __restrict__ sqv,
    int* __restrict__ idxh)
{
    __shared__ unsigned int mlist[8][16][17];
    const int tid  = threadIdx.x;
    const int wv   = tid >> 6;
    const int lane = tid & 63;
    const int r = lane & 15, g = lane >> 4;
    const int b    = blockIdx.y;
    const int qt   = blockIdx.x >> 1;
    const int half = blockIdx.x & 1;
    const int qs = wv >> 1, mq = wv & 1;
    const int tq   = qt * 4 + qs;
    const int tm0  = half * 128 + mq * 64;
    const unsigned short* fp = featP + (size_t)b * NPT * CH;

    short8 bq0, bq1, bq2, bq3, bq4, bq5;
    {
        const unsigned short* qp = fp + (size_t)tq * 3072 + lane * 8;
        bq0 = *reinterpret_cast<const short8*>(qp);
        bq1 = *reinterpret_cast<const short8*>(qp + 512);
        bq2 = *reinterpret_cast<const short8*>(qp + 1024);
        bq3 = *reinterpret_cast<const short8*>(qp + 1536);
        bq4 = *reinterpret_cast<const short8*>(qp + 2048);
        bq5 = *reinterpret_cast<const short8*>(qp + 2560);
    }

    unsigned int Q[16];
    #pragma unroll
    for (int e = 0; e < 16; ++e) Q[e] = 0xFFFFFFFFu;

    const float* sq = sqv + b * NPT;
    const unsigned short* pa = fp + (size_t)tm0 * 3072 + lane * 8;

    for (int it = 0; it < 64; ++it){
        const unsigned short* p = pa + (size_t)it * 3072;
        short8 a0 = *reinterpret_cast<const short8*>(p);
        short8 a1 = *reinterpret_cast<const short8*>(p + 512);
        short8 a2 = *reinterpret_cast<const short8*>(p + 1024);
        short8 a3 = *reinterpret_cast<const short8*>(p + 1536);
        short8 a4 = *reinterpret_cast<const short8*>(p + 2048);
        short8 a5 = *reinterpret_cast<const short8*>(p + 2560);
        const int tm = tm0 + it;
        float4 s4 = *reinterpret_cast<const float4*>(sq + tm * 16 + 4 * g);

        f32x4 acc = {0.f, 0.f, 0.f, 0.f};
        acc = __builtin_amdgcn_mfma_f32_16x16x32_bf16(a0, bq0, acc, 0, 0, 0);
        acc = __builtin_amdgcn_mfma_f32_16x16x32_bf16(a1, bq1, acc, 0, 0, 0);
        acc = __builtin_amdgcn_mfma_f32_16x16x32_bf16(a2, bq2, acc, 0, 0, 0);
        acc = __builtin_amdgcn_mfma_f32_16x16x32_bf16(a3, bq3, acc, 0, 0, 0);
        acc = __builtin_amdgcn_mfma_f32_16x16x32_bf16(a4, bq4, acc, 0, 0, 0);
        acc = __builtin_amdgcn_mfma_f32_16x16x32_bf16(a5, bq5, acc, 0, 0, 0);

        const int m0 = tm * 16 + 4 * g;
        float sa[4] = {s4.x, s4.y, s4.z, s4.w};
        #pragma unroll
        for (int u = 0; u < 4; ++u){
            float d = fmaxf(fmaf(-2.0f, acc[u], sa[u]), 0.0f);
            unsigned int k = (__builtin_bit_cast(unsigned int, d) & 0xFFFFF000u)
                           | (unsigned int)(m0 + u);
            #pragma unroll
            for (int pz = 0; pz < 8; ++pz){
                unsigned int a = Q[2 * pz], bv = Q[2 * pz + 1];
                Q[2 * pz]     = umin_(a, k);
                Q[2 * pz + 1] = umed3_(a, bv, k);
                k             = umax_(bv, k);
            }
        }
    }

    // per-wave extraction: top-16 across the 4 g-lanes per query (keys unique)
    #pragma unroll 1
    for (int rd = 0; rd < 16; ++rd){
        unsigned int v = Q[0];
        v = umin_(v, (unsigned int)__shfl_xor((int)v, 16));
        v = umin_(v, (unsigned int)__shfl_xor((int)v, 32));
        bool win = (Q[0] == v);
        if (win){
            #pragma unroll
            for (int e = 0; e < 15; ++e) Q[e] = Q[e + 1];
            Q[15] = 0xFFFFFFFFu;
        }
        if (g == 0) mlist[wv][r][rd] = v;
    }
    if (g == 0) mlist[wv][r][16] = 0xFFFFFFFFu;
    __syncthreads();

    // merge the 2 m-quarter wave-lists per query -> top-16 for this half (keys unique)
    if (tid < 64){
        const int qsub = tid >> 4, rr = tid & 15;
        int i0 = 0, i1 = 0;
        int* op = idxh + ((size_t)(b * NPT + qt * 64 + qsub * 16 + rr) * 2 + half) * KPH;
        for (int rd = 0; rd < KPH; ++rd){
            unsigned int k0 = mlist[qsub * 2][rr][i0];
            unsigned int k1 = mlist[qsub * 2 + 1][rr][i1];
            unsigned int mm = umin_(k0, k1);
            op[rd] = (int)(mm & 0xFFFu);
            i0 += (k0 == mm); i1 += (k1 == mm);
        }
    }
}

// ---------------- fused refine v4: 2 queries/wave, 32-lane groups, certified f64 fallback -------
__global__ __launch_bounds__(256) void k_refine(
    const float* __restrict__ feat32, const double* __restrict__ featT,
    const int* __restrict__ idxh, int* __restrict__ idxf)
{
    const int q = blockIdx.x * 8 + (threadIdx.x >> 5);
    const int b = blockIdx.y;
    const int sl = threadIdx.x & 31;
    const int* cl = idxh + ((size_t)b * NPT + q) * KCAND;
    const float* qv = feat32 + ((size_t)b * NPT + q) * CH;
    float qr[6];
    #pragma unroll
    for (int j = 0; j < 6; ++j) qr[j] = qv[sl + 32 * j];

    float myd = INFINITY; int mym = 0x7fffffff;
    #pragma unroll
    for (int t0 = 0; t0 < KCAND; t0 += 8){
        float pd[8]; int cm[8];
        #pragma unroll
        for (int j = 0; j < 8; ++j){
            int m = cl[t0 + j];
            cm[j] = m;
            const float* cv = feat32 + ((size_t)b * NPT + m) * CH;
            float d = 0.f;
            #pragma unroll
            for (int e = 0; e < 6; ++e){
                float dv = cv[sl + 32 * e] - qr[e];
                d = fmaf(dv, dv, d);
            }
            pd[j] = d;
        }
        #pragma unroll
        for (int j = 0; j < 8; ++j){
            float d = pd[j];
            #pragma unroll
            for (int off = 16; off; off >>= 1) d += __shfl_xor(d, off, 32);
            if (sl == t0 + j){ myd = d; mym = cm[j]; }
        }
    }

    float d16 = 0.f;
    for (int r = 0; r < KNB; ++r){
        float bv = myd; int bi = mym;
        #pragma unroll
        for (int off = 16; off; off >>= 1){
            float ov = __shfl_xor(bv, off, 32);
            int   oi = __shfl_xor(bi, off, 32);
            if (ov < bv || (ov == bv && oi < bi)){ bv = ov; bi = oi; }
        }
        if (sl == 0) idxf[((size_t)b * NPT + q) * KNB + r] = bi;
        if (mym == bi){ myd = INFINITY; mym = 0x7fffffff; }
        d16 = bv;
    }
    float b17 = myd;
    #pragma unroll
    for (int off = 16; off; off >>= 1) b17 = fminf(b17, __shfl_xor(b17, off, 32));
    int flag = (b17 - d16 < 1e-3f + 2e-4f * d16) ? 1 : 0;
    flag = __shfl(flag, 0, 32);
    if (!flag) return;

    // exact f64 re-rank (rare; 32-lane group)
    const double* qvd = featT + ((size_t)b * NPT + q) * CH;
    double qrd[6];
    #pragma unroll
    for (int j = 0; j < 6; ++j) qrd[j] = qvd[sl + 32 * j];
    double mydd = INFINITY; int mymd = 0x7fffffff;
    for (int t = 0; t < KCAND; ++t){
        int m = cl[t];
        const double* cv = featT + ((size_t)b * NPT + m) * CH;
        double d = 0.;
        #pragma unroll
        for (int e = 0; e < 6; ++e){
            double dv = cv[sl + 32 * e] - qrd[e];
            d = fma(dv, dv, d);
        }
        #pragma unroll
        for (int off = 16; off; off >>= 1) d += __shfl_xor(d, off, 32);
        if (sl == t){ mydd = d; mymd = m; }
    }
    for (int r = 0; r < KNB; ++r){
        double bv = mydd; int bi = mymd;
        #pragma unroll
        for (int off = 16; off; off >>= 1){
            double ov = __shfl_xor(bv, off, 32);
            int    oi = __shfl_xor(bi, off, 32);
            if (ov < bv || (ov == bv && oi < bi)){ bv = ov; bi = oi; }
        }
        if (sl == 0) idxf[((size_t)b * NPT + q) * KNB + r] = bi;
        if (mymd == bi){ mydd = INFINITY; mymd = 0x7fffffff; }
    }
}

// ---------------- gather v2: coalesced rows + LDS-transposed hcat write -------------------------
__global__ __launch_bounds__(128) void k_gather2(
    const float* __restrict__ feat32, const float* __restrict__ sh0,
    const int* __restrict__ idx, float* __restrict__ hcat)
{
    __shared__ float lt[192 * 33];
    __shared__ int il[32 * KNB];
    const int tid = threadIdx.x;
    const int n0  = blockIdx.x * 32;
    const int cg  = blockIdx.y;
    const int b   = blockIdx.z;

    for (int i = tid; i < 32 * KNB; i += 128)
        il[i] = idx[((size_t)b * NPT + n0) * KNB + i];
    __syncthreads();

    const int nl = tid >> 2, sub = tid & 3;
    const int n  = n0 + nl;
    const float* fbase = feat32 + (size_t)b * NPT * CH;
    const float* qr = fbase + (size_t)n * CH + cg * 96;

    float4 qv[6], mx[6];
    #pragma unroll
    for (int j = 0; j < 6; ++j){
        qv[j] = *reinterpret_cast<const float4*>(qr + (sub + 4 * j) * 4);
        mx[j] = make_float4(-INFINITY, -INFINITY, -INFINITY, -INFINITY);
    }

    #pragma unroll 4
    for (int k = 0; k < KNB; ++k){
        const float* cr = fbase + (size_t)il[nl * KNB + k] * CH + cg * 96;
        #pragma unroll
        for (int j = 0; j < 6; ++j){
            float4 v = *reinterpret_cast<const float4*>(cr + (sub + 4 * j) * 4);
            mx[j].x = fmaxf(mx[j].x, v.x - qv[j].x);
            mx[j].y = fmaxf(mx[j].y, v.y - qv[j].y);
            mx[j].z = fmaxf(mx[j].z, v.z - qv[j].z);
            mx[j].w = fmaxf(mx[j].w, v.w - qv[j].w);
        }
    }

    #pragma unroll
    for (int j = 0; j < 6; ++j){
        const int cb = (sub + 4 * j) * 4;
        float4 s4 = *reinterpret_cast<const float4*>(sh0 + cg * 96 + cb);
        float fi[4] = {qv[j].x + s4.x, qv[j].y + s4.y, qv[j].z + s4.z, qv[j].w + s4.w};
        float mm[4] = {mx[j].x, mx[j].y, mx[j].z, mx[j].w};
        #pragma unroll
        for (int e = 0; e < 4; ++e){
            int cl = cb + e;
            lt[(2 * cl) * 33 + nl]     = fi[e];
            lt[(2 * cl + 1) * 33 + nl] = mm[e];
        }
    }
    __syncthreads();

    const int rsub = tid >> 5;
    const int ni   = tid & 31;
    for (int r0 = 0; r0 < 192; r0 += 4){
        int row = r0 + rsub;
        int ch  = cg * 192 + row;
        hcat[((size_t)b * 2 * CH + ch) * NPT + n0 + ni] = lt[row * 33 + ni];
    }
}

// ---------------- mr-conv GEMM (K=384) + bias, with fused BN1-stat atomics ----------------------
__global__ __launch_bounds__(256) void k_gemm_mr(
    const float* __restrict__ in, const float* __restrict__ W, const float* __restrict__ bias,
    float* __restrict__ out, float* __restrict__ s1sum, float* __restrict__ s1sq)
{
    constexpr int KDIM = 2 * CH, OT = 8, NT = 4;
    __shared__ float wtT[KDIM][OT];
    __shared__ float redS[4][8], redQ[4][8];
    const int tid = threadIdx.x;
    const int o0  = blockIdx.y * OT;
    const int b   = blockIdx.z;
    const int n   = blockIdx.x * (256 * NT) + tid * NT;

    for (int lin = tid; lin < KDIM * OT; lin += 256){
        int c = lin >> 3, o = lin & 7;
        wtT[c][o] = W[(size_t)(o0 + o) * KDIM + c];
    }
    __syncthreads();

    float acc[OT][NT] = {};
    const float* ip = in + (size_t)b * KDIM * NPT + n;
    #pragma unroll 2
    for (int c = 0; c < KDIM; ++c){
        float4 x4 = *reinterpret_cast<const float4*>(ip + (size_t)c * NPT);
        float xv[NT] = {x4.x, x4.y, x4.z, x4.w};
        float4 w0 = *reinterpret_cast<const float4*>(&wtT[c][0]);
        float4 w1 = *reinterpret_cast<const float4*>(&wtT[c][4]);
        float wv[OT] = {w0.x, w0.y, w0.z, w0.w, w1.x, w1.y, w1.z, w1.w};
        #pragma unroll
        for (int oo = 0; oo < OT; ++oo)
            #pragma unroll
            for (int j = 0; j < NT; ++j)
                acc[oo][j] = fmaf(wv[oo], xv[j], acc[oo][j]);
    }

    float ps[OT], pq[OT];
    #pragma unroll
    for (int oo = 0; oo < OT; ++oo){
        size_t off = ((size_t)b * CH + o0 + oo) * NPT + n;
        float add = bias[o0 + oo];
        float vals[4];
        float s = 0.f, q = 0.f;
        #pragma unroll
        for (int j = 0; j < 4; ++j){
            vals[j] = acc[oo][j] + add;
            s += vals[j];
            q = fmaf(vals[j], vals[j], q);
        }
        ps[oo] = s; pq[oo] = q;
        float4 o4; o4.x = vals[0]; o4.y = vals[1]; o4.z = vals[2]; o4.w = vals[3];
        *reinterpret_cast<float4*>(out + off) = o4;
    }

    #pragma unroll
    for (int oo = 0; oo < OT; ++oo){
        #pragma unroll
        for (int off = 32; off; off >>= 1){
            ps[oo] += __shfl_xor(ps[oo], off);
            pq[oo] += __shfl_xor(pq[oo], off);
        }
    }
    const int wv = tid >> 6, lane = tid & 63;
    if (lane == 0){
        #pragma unroll
        for (int oo = 0; oo < OT; ++oo){ redS[wv][oo] = ps[oo]; redQ[wv][oo] = pq[oo]; }
    }
    __syncthreads();
    if (tid < 8){
        float s = redS[0][tid] + redS[1][tid] + redS[2][tid] + redS[3][tid];
        float q = redQ[0][tid] + redQ[1][tid] + redQ[2][tid] + redQ[3][tid];
        atomicAdd(&s1sum[o0 + tid], s);
        atomicAdd(&s1sq[o0 + tid], q);
    }
}

// ---------------- u = gelu(gelu(BN1(t2))), BN1 from sums; fused BN2-stat atomics ----------------
__global__ __launch_bounds__(256) void k_u(
    const float* __restrict__ in, const float* __restrict__ s1sum, const float* __restrict__ s1sq,
    const float* __restrict__ gm, const float* __restrict__ bm,
    float* __restrict__ out, float* __restrict__ s2sum, float* __restrict__ s2sq)
{
    __shared__ float redS[4], redQ[4];
    const int c = blockIdx.y, b = blockIdx.z;
    const int n = (blockIdx.x * 256 + threadIdx.x) * 4;
    const float invn = 1.0f / NTOT;
    float mean = s1sum[c] * invn;
    float var  = s1sq[c] * invn - mean * mean;
    float rstd = rsqrtf(var + 1e-5f);
    float s = rstd * gm[c], t = bm[c] - mean * s;

    size_t i = ((size_t)b * CH + c) * NPT + n;
    float4 v = *reinterpret_cast<const float4*>(in + i);
    float4 o;
    o.x = gelu_exact(gelu_exact(fmaf(v.x, s, t)));
    o.y = gelu_exact(gelu_exact(fmaf(v.y, s, t)));
    o.z = gelu_exact(gelu_exact(fmaf(v.z, s, t)));
    o.w = gelu_exact(gelu_exact(fmaf(v.w, s, t)));
    *reinterpret_cast<float4*>(out + i) = o;

    float ps = o.x + o.y + o.z + o.w;
    float pq = fmaf(o.x, o.x, fmaf(o.y, o.y, fmaf(o.z, o.z, o.w * o.w)));
    #pragma unroll
    for (int off = 32; off; off >>= 1){
        ps += __shfl_xor(ps, off);
        pq += __shfl_xor(pq, off);
    }
    const int wv = threadIdx.x >> 6, lane = threadIdx.x & 63;
    if (lane == 0){ redS[wv] = ps; redQ[wv] = pq; }
    __syncthreads();
    if (threadIdx.x == 0){
        atomicAdd(&s2sum[c], redS[0] + redS[1] + redS[2] + redS[3]);
        atomicAdd(&s2sq[c],  redQ[0] + redQ[1] + redQ[2] + redQ[3]);
    }
}

// ---------------- fc2 GEMM with BN2 (from sums) folded into input + residual --------------------
__global__ __launch_bounds__(256) void k_gemm_fc2(
    const float* __restrict__ in, const float* __restrict__ W,
    const float* __restrict__ s2sum, const float* __restrict__ s2sq,
    const float* __restrict__ g1, const float* __restrict__ b1,
    const float* __restrict__ resid, float* __restrict__ out)
{
    constexpr int KDIM = CH, OT = 8, NT = 4;
    __shared__ float wtT[KDIM][OT];
    __shared__ float scl[KDIM], shl[KDIM];
    const int tid = threadIdx.x;
    const int o0  = blockIdx.y * OT;
    const int b   = blockIdx.z;
    const int n   = blockIdx.x * (256 * NT) + tid * NT;

    for (int lin = tid; lin < KDIM * OT; lin += 256){
        int c = lin >> 3, o = lin & 7;
        wtT[c][o] = W[(size_t)(o0 + o) * KDIM + c];
    }
    const float invn = 1.0f / NTOT;
    for (int c = tid; c < KDIM; c += 256){
        float mean = s2sum[c] * invn;
        float var  = s2sq[c] * invn - mean * mean;
        float rstd = rsqrtf(var + 1e-5f);
        float s = rstd * g1[c];
        scl[c] = s;
        shl[c] = b1[c] - mean * s;
    }
    __syncthreads();

    float acc[OT][NT] = {};
    const float* ip = in + (size_t)b * KDIM * NPT + n;
    #pragma unroll 2
    for (int c = 0; c < KDIM; ++c){
        float4 x4 = *reinterpret_cast<const float4*>(ip + (size_t)c * NPT);
        float xv[NT];
        xv[0] = fmaf(x4.x, scl[c], shl[c]);
        xv[1] = fmaf(x4.y, scl[c], shl[c]);
        xv[2] = fmaf(x4.z, scl[c], shl[c]);
        xv[3] = fmaf(x4.w, scl[c], shl[c]);
        float4 w0 = *reinterpret_cast<const float4*>(&wtT[c][0]);
        float4 w1 = *reinterpret_cast<const float4*>(&wtT[c][4]);
        float wv[OT] = {w0.x, w0.y, w0.z, w0.w, w1.x, w1.y, w1.z, w1.w};
        #pragma unroll
        for (int oo = 0; oo < OT; ++oo)
            #pragma unroll
            for (int j = 0; j < NT; ++j)
                acc[oo][j] = fmaf(wv[oo], xv[j], acc[oo][j]);
    }

    #pragma unroll
    for (int oo = 0; oo < OT; ++oo){
        size_t off = ((size_t)b * CH + o0 + oo) * NPT + n;
        float4 r4 = *reinterpret_cast<const float4*>(resid + off);
        float4 o4;
        o4.x = acc[oo][0] + r4.x; o4.y = acc[oo][1] + r4.y;
        o4.z = acc[oo][2] + r4.z; o4.w = acc[oo][3] + r4.w;
        *reinterpret_cast<float4*>(out + off) = o4;
    }
}

extern "C" void kernel_launch(void* const* d_in, const int* in_sizes, int n_in,
                              void* d_out, int out_size, void* d_ws, size_t ws_size,
                              hipStream_t stream)
{
    const float* x    = (const float*)d_in[0];
    const float* w1   = (const float*)d_in[1];
    const float* w2   = (const float*)d_in[2];
    const float* wmr  = (const float*)d_in[3];
    const float* bmr  = (const float*)d_in[4];
    const float* g0   = (const float*)d_in[5];
    const float* b0   = (const float*)d_in[6];
    const float* gm   = (const float*)d_in[7];
    const float* bm   = (const float*)d_in[8];
    const float* g1   = (const float*)d_in[9];
    const float* b1   = (const float*)d_in[10];
    float* outp = (float*)d_out;

    const size_t BCN = (size_t)BSZ * CH * NPT;
    float*  A      = (float*)d_ws;                       // BCN f32: t2
    float*  Bb     = A + BCN;                            // BCN f32: featP (bf16) -> u
    unsigned short* featP = (unsigned short*)Bb;
    float*  Cc     = Bb + BCN;                           // 2*BCN f32: t1d (f64) -> hcat
    double* t1d    = (double*)Cc;
    double* featT  = (double*)(Cc + 2 * BCN);            // BCN f64
    float*  feat32 = (float*)(featT + BCN);              // BCN f32
    float*  sqv    = feat32 + BCN;                       // B*N
    int*    idxh   = (int*)(sqv + (size_t)BSZ * NPT);    // B*N*32
    int*    idxf   = idxh + (size_t)BSZ * NPT * KCAND;   // B*N*16
    float*  bnacc  = (float*)(idxf + (size_t)BSZ * NPT * KNB);  // 4*CH f32
    float *s1sum = bnacc, *s1sq = bnacc + CH, *s2sum = bnacc + 2 * CH, *s2sq = bnacc + 3 * CH;
    double* scd    = (double*)(bnacc + 4 * CH);
    float*  scb    = (float*)(scd + CH);
    float *sc0 = scb, *sh0 = scb + CH;

    dim3 gg(NPT / 1024, CH / 8, BSZ);
    dim3 ge(NPT / 1024, CH, BSZ);

    hipMemsetAsync(bnacc, 0, 4 * CH * sizeof(float), stream);
    // fc1 (f64 accumulate)
    k_fc1_f64<<<gg, 256, 0, stream>>>(x, w1, t1d);
    // BN0 stats in f64
    k_stats_f64<<<CH, 256, 0, stream>>>(t1d, g0, b0, sc0, sh0, scd);
    // fused transpose/scale -> featT + feat32 + featP(fragment layout) + sqv
    k_feat<<<dim3(NPT / 32, BSZ), dim3(32, 8), 0, stream>>>(t1d, scd, featT, feat32, featP, sqv);
    // kNN prefilter (fragment loads + med3 insert, top-16/half)
    k_knn_mfma<<<dim3(2 * NPT / 64, BSZ), 512, 0, stream>>>(featP, sqv, idxh);
    // fused refine v4 (2 q/wave, 32-candidate, certified f64 fallback)
    k_refine<<<dim3(NPT / 8, BSZ), 256, 0, stream>>>(feat32, featT, idxh, idxf);
    // gather (coalesced; writes hcat over dead t1d)
    k_gather2<<<dim3(NPT / 32, 2, BSZ), 128, 0, stream>>>(feat32, sh0, idxf, Cc);
    // mr conv + bias + BN1-stat atomics
    k_gemm_mr<<<gg, 256, 0, stream>>>(Cc, wmr, bmr, A, s1sum, s1sq);
    // u = gelu(gelu(BN1(t2))) + BN2-stat atomics
    k_u<<<ge, 256, 0, stream>>>(A, s1sum, s1sq, gm, bm, Bb, s2sum, s2sq);
    // fc2 with BN2 folded + residual
    k_gemm_fc2<<<gg, 256, 0, stream>>>(Bb, w2, s2sum, s2sq, g1, b1, x, outp);
}

// Round 19
// 372.078 us; speedup vs baseline: 1.3035x; 1.1413x over previous
//
#include <hip/hip_runtime.h>
#include <hip/hip_bf16.h>
#include <math.h>

#define BSZ 4
#define NPT 4096
#define CH  192
#define KNB 16
#define KPH 16              // kept per half (top-16/half provably suffices)
#define KCAND (2 * KPH)     // 32 refine candidates
#define NTOT ((float)(BSZ * NPT))
#define NT64 ((double)(BSZ * NPT))

typedef short short8 __attribute__((ext_vector_type(8)));
typedef float f32x4  __attribute__((ext_vector_type(4)));

__device__ __forceinline__ float gelu_exact(float x){
    return 0.5f * x * (1.0f + erff(x * 0.70710678118654752440f));
}
__device__ __forceinline__ unsigned int umin_(unsigned int a, unsigned int b){ return a < b ? a : b; }
__device__ __forceinline__ unsigned int umax_(unsigned int a, unsigned int b){ return a < b ? b : a; }
__device__ __forceinline__ unsigned int umed3_(unsigned int a, unsigned int b, unsigned int c){
    unsigned int r;
    asm("v_med3_u32 %0, %1, %2, %3" : "=v"(r) : "v"(a), "v"(b), "v"(c));
    return r;
}
__device__ __forceinline__ unsigned short bf16rnd(float v){
    unsigned int bits = __builtin_bit_cast(unsigned int, v);
    return (unsigned short)((bits + 0x7fff + ((bits >> 16) & 1)) >> 16);
}

// ---------------- fc1 (f64 accumulate) -> f64 t1, with fused BN0-stat f64 atomics ---------------
__global__ __launch_bounds__(256) void k_fc1_f64(
    const float* __restrict__ in, const float* __restrict__ W, double* __restrict__ outd,
    double* __restrict__ s0sum, double* __restrict__ s0sq)
{
    constexpr int OT = 8, NT = 4;
    __shared__ float wtT[CH][OT];
    __shared__ double redS[4][8], redQ[4][8];
    const int tid = threadIdx.x;
    const int o0  = blockIdx.y * OT;
    const int b   = blockIdx.z;
    const int n   = blockIdx.x * (256 * NT) + tid * NT;

    for (int lin = tid; lin < CH * OT; lin += 256){
        int c = lin >> 3, o = lin & 7;
        wtT[c][o] = W[(size_t)(o0 + o) * CH + c];
    }
    __syncthreads();

    double acc[OT][NT] = {};
    const float* ip = in + (size_t)b * CH * NPT + n;
    for (int c = 0; c < CH; ++c){
        float4 x4 = *reinterpret_cast<const float4*>(ip + (size_t)c * NPT);
        double xv[NT] = {x4.x, x4.y, x4.z, x4.w};
        float4 w0 = *reinterpret_cast<const float4*>(&wtT[c][0]);
        float4 w1 = *reinterpret_cast<const float4*>(&wtT[c][4]);
        double wv[OT] = {w0.x, w0.y, w0.z, w0.w, w1.x, w1.y, w1.z, w1.w};
        #pragma unroll
        for (int oo = 0; oo < OT; ++oo)
            #pragma unroll
            for (int j = 0; j < NT; ++j)
                acc[oo][j] = fma(wv[oo], xv[j], acc[oo][j]);
    }

    double ps[OT], pq[OT];
    #pragma unroll
    for (int oo = 0; oo < OT; ++oo){
        size_t off = ((size_t)b * CH + o0 + oo) * NPT + n;
        double s = 0., q = 0.;
        #pragma unroll
        for (int j = 0; j < 4; ++j){
            double v = acc[oo][j];
            outd[off + j] = v;
            s += v; q = fma(v, v, q);
        }
        ps[oo] = s; pq[oo] = q;
    }

    #pragma unroll
    for (int oo = 0; oo < OT; ++oo){
        #pragma unroll
        for (int off = 32; off; off >>= 1){
            ps[oo] += __shfl_xor(ps[oo], off);
            pq[oo] += __shfl_xor(pq[oo], off);
        }
    }
    const int wv = tid >> 6, lane = tid & 63;
    if (lane == 0){
        #pragma unroll
        for (int oo = 0; oo < OT; ++oo){ redS[wv][oo] = ps[oo]; redQ[wv][oo] = pq[oo]; }
    }
    __syncthreads();
    if (tid < 8){
        double s = redS[0][tid] + redS[1][tid] + redS[2][tid] + redS[3][tid];
        double q = redQ[0][tid] + redQ[1][tid] + redQ[2][tid] + redQ[3][tid];
        atomicAdd(&s0sum[o0 + tid], s);
        atomicAdd(&s0sq[o0 + tid], q);
    }
}

// ---------------- fused: transpose+scale -> featT(f64), feat32, featP (MFMA-fragment bf16), sqv -
// BN0 scale computed inline from fused sums.
__global__ void k_feat(
    const double* __restrict__ t1d, const float* __restrict__ g0,
    const double* __restrict__ s0sum, const double* __restrict__ s0sq,
    double* __restrict__ featT, float* __restrict__ feat32,
    unsigned short* __restrict__ featP, float* __restrict__ sqv)
{
    __shared__ double tile[32][33];
    __shared__ float sqp[32][33];
    __shared__ double scdl[CH];
    const int n0 = blockIdx.x * 32, b = blockIdx.y;
    const int tx = threadIdx.x, ty = threadIdx.y;
    const int tid = ty * 32 + tx;
    float part[4] = {0.f, 0.f, 0.f, 0.f};
    unsigned short* fpb = featP + (size_t)b * NPT * CH;

    for (int i = tid; i < CH; i += 256){
        double mean = s0sum[i] / NT64;
        double var  = s0sq[i] / NT64 - mean * mean;
        scdl[i] = (1.0 / sqrt(var + 1e-5)) * (double)g0[i];
    }
    __syncthreads();

    for (int cc = 0; cc < CH / 32; ++cc){
        const int cbase = cc * 32;
        #pragma unroll
        for (int r = 0; r < 32; r += 8){
            int c = cbase + ty + r;
            tile[ty + r][tx] = t1d[((size_t)b * CH + c) * NPT + n0 + tx] * scdl[c];
        }
        __syncthreads();
        #pragma unroll
        for (int r = 0; r < 32; r += 8){
            int n = n0 + ty + r;
            int c = cbase + tx;
            double v = tile[tx][ty + r];
            size_t o = ((size_t)b * NPT + n) * CH + c;
            featT[o] = v;
            float f = (float)v;
            feat32[o] = f;
            part[r >> 3] = fmaf(f, f, part[r >> 3]);
        }
        if (tid < 128){
            const int t_ = tid >> 6;
            const int l  = tid & 63;
            const int r_ = l & 15, g_ = l >> 4;
            const int nl = t_ * 16 + r_;
            short8 pk;
            #pragma unroll
            for (int e = 0; e < 8; ++e)
                pk[e] = (short)bf16rnd((float)tile[g_ * 8 + e][nl]);
            const int tP = blockIdx.x * 2 + t_;
            *reinterpret_cast<short8*>(fpb + (size_t)(tP * 6 + cc) * 512 + l * 8) = pk;
        }
        __syncthreads();
    }
    #pragma unroll
    for (int j = 0; j < 4; ++j) sqp[ty + 8 * j][tx] = part[j];
    __syncthreads();
    if (ty == 0){
        float s = 0.f;
        #pragma unroll 8
        for (int k = 0; k < 32; ++k) s += sqp[tx][k];
        sqv[b * NPT + n0 + tx] = s;
    }
}

// ---------------- MFMA kNN prefilter v12: 1024 thr (16 waves), m-eighth waves -------------------
// grid (2*NPT/64, BSZ) = (128,4), 2 blocks/CU -> 32 waves/CU (100% headroom).
// wave wv: q-sub (wv>>2, 16 q), m-eighth (wv&3, 512 m = 32 tiles). Lane-contiguous fragment
// loads (featP); med3 pair-chain insert; clamped-nonneg distance keys (refine re-ranks exactly).
__global__ __launch_bounds__(1024, 8) void k_knn_mfma(
    const unsigned short* __restrict__ featP, const float* __restrict__ sqv,
    int* __restrict__ idxh)
{
    __shared__ unsigned int mlist[16][16][17];     // 17.4 KB
    const int tid  = threadIdx.x;
    const int wv   = tid >> 6;
    const int lane = tid & 63;
    const int r = lane & 15, g = lane >> 4;
    const int b    = blockIdx.y;
    const int qt   = blockIdx.x >> 1;
    const int half = blockIdx.x & 1;
    const int qs = wv >> 2, me = wv & 3;
    const int tq   = qt * 4 + qs;
    const int tm0  = half * 128 + me * 32;
    const unsigned short* fp = featP + (size_t)b * NPT * CH;

    short8 bq0, bq1, bq2, bq3, bq4, bq5;
    {
        const unsigned short* qp = fp + (size_t)tq * 3072 + lane * 8;
        bq0 = *reinterpret_cast<const short8*>(qp);
        bq1 = *reinterpret_cast<const short8*>(qp + 512);
        bq2 = *reinterpret_cast<const short8*>(qp + 1024);
        bq3 = *reinterpret_cast<const short8*>(qp + 1536);
        bq4 = *reinterpret_cast<const short8*>(qp + 2048);
        bq5 = *reinterpret_cast<const short8*>(qp + 2560);
    }

    unsigned int Q[16];
    #pragma unroll
    for (int e = 0; e < 16; ++e) Q[e] = 0xFFFFFFFFu;

    const float* sq = sqv + b * NPT;
    const unsigned short* pa = fp + (size_t)tm0 * 3072 + lane * 8;

    for (int it = 0; it < 32; ++it){
        const unsigned short* p = pa + (size_t)it * 3072;
        short8 a0 = *reinterpret_cast<const short8*>(p);
        short8 a1 = *reinterpret_cast<const short8*>(p + 512);
        short8 a2 = *reinterpret_cast<const short8*>(p + 1024);
        short8 a3 = *reinterpret_cast<const short8*>(p + 1536);
        short8 a4 = *reinterpret_cast<const short8*>(p + 2048);
        short8 a5 = *reinterpret_cast<const short8*>(p + 2560);
        const int tm = tm0 + it;
        float4 s4 = *reinterpret_cast<const float4*>(sq + tm * 16 + 4 * g);

        f32x4 acc = {0.f, 0.f, 0.f, 0.f};
        acc = __builtin_amdgcn_mfma_f32_16x16x32_bf16(a0, bq0, acc, 0, 0, 0);
        acc = __builtin_amdgcn_mfma_f32_16x16x32_bf16(a1, bq1, acc, 0, 0, 0);
        acc = __builtin_amdgcn_mfma_f32_16x16x32_bf16(a2, bq2, acc, 0, 0, 0);
        acc = __builtin_amdgcn_mfma_f32_16x16x32_bf16(a3, bq3, acc, 0, 0, 0);
        acc = __builtin_amdgcn_mfma_f32_16x16x32_bf16(a4, bq4, acc, 0, 0, 0);
        acc = __builtin_amdgcn_mfma_f32_16x16x32_bf16(a5, bq5, acc, 0, 0, 0);

        const int m0 = tm * 16 + 4 * g;
        float sa[4] = {s4.x, s4.y, s4.z, s4.w};
        #pragma unroll
        for (int u = 0; u < 4; ++u){
            float d = fmaxf(fmaf(-2.0f, acc[u], sa[u]), 0.0f);
            unsigned int k = (__builtin_bit_cast(unsigned int, d) & 0xFFFFF000u)
                           | (unsigned int)(m0 + u);
            #pragma unroll
            for (int pz = 0; pz < 8; ++pz){
                unsigned int a = Q[2 * pz], bv = Q[2 * pz + 1];
                Q[2 * pz]     = umin_(a, k);
                Q[2 * pz + 1] = umed3_(a, bv, k);
                k             = umax_(bv, k);
            }
        }
    }

    // per-wave extraction: top-16 across the 4 g-lanes per query (keys unique)
    #pragma unroll 1
    for (int rd = 0; rd < 16; ++rd){
        unsigned int v = Q[0];
        v = umin_(v, (unsigned int)__shfl_xor((int)v, 16));
        v = umin_(v, (unsigned int)__shfl_xor((int)v, 32));
        bool win = (Q[0] == v);
        if (win){
            #pragma unroll
            for (int e = 0; e < 15; ++e) Q[e] = Q[e + 1];
            Q[15] = 0xFFFFFFFFu;
        }
        if (g == 0) mlist[wv][r][rd] = v;
    }
    if (g == 0) mlist[wv][r][16] = 0xFFFFFFFFu;   // sentinel
    __syncthreads();

    // merge 4 sorted eighth-lists per query -> top-16 for this half (keys unique)
    if (tid < 64){
        const int qq = tid;                 // query within 64-q tile
        const int q2 = qq >> 4, rr = qq & 15;
        int i0 = 0, i1 = 0, i2 = 0, i3 = 0;
        int* op = idxh + ((size_t)(b * NPT + qt * 64 + qq) * 2 + half) * KPH;
        for (int rd = 0; rd < KPH; ++rd){
            unsigned int k0 = mlist[q2 * 4 + 0][rr][i0];
            unsigned int k1 = mlist[q2 * 4 + 1][rr][i1];
            unsigned int k2 = mlist[q2 * 4 + 2][rr][i2];
            unsigned int k3 = mlist[q2 * 4 + 3][rr][i3];
            unsigned int mm = umin_(umin_(k0, k1), umin_(k2, k3));
            op[rd] = (int)(mm & 0xFFFu);
            i0 += (k0 == mm); i1 += (k1 == mm); i2 += (k2 == mm); i3 += (k3 == mm);
        }
    }
}

// ---------------- fused refine v4: 2 queries/wave, 32-lane groups, certified f64 fallback -------
__global__ __launch_bounds__(256) void k_refine(
    const float* __restrict__ feat32, const double* __restrict__ featT,
    const int* __restrict__ idxh, int* __restrict__ idxf)
{
    const int q = blockIdx.x * 8 + (threadIdx.x >> 5);
    const int b = blockIdx.y;
    const int sl = threadIdx.x & 31;
    const int* cl = idxh + ((size_t)b * NPT + q) * KCAND;
    const float* qv = feat32 + ((size_t)b * NPT + q) * CH;
    float qr[6];
    #pragma unroll
    for (int j = 0; j < 6; ++j) qr[j] = qv[sl + 32 * j];

    float myd = INFINITY; int mym = 0x7fffffff;
    #pragma unroll
    for (int t0 = 0; t0 < KCAND; t0 += 8){
        float pd[8]; int cm[8];
        #pragma unroll
        for (int j = 0; j < 8; ++j){
            int m = cl[t0 + j];
            cm[j] = m;
            const float* cv = feat32 + ((size_t)b * NPT + m) * CH;
            float d = 0.f;
            #pragma unroll
            for (int e = 0; e < 6; ++e){
                float dv = cv[sl + 32 * e] - qr[e];
                d = fmaf(dv, dv, d);
            }
            pd[j] = d;
        }
        #pragma unroll
        for (int j = 0; j < 8; ++j){
            float d = pd[j];
            #pragma unroll
            for (int off = 16; off; off >>= 1) d += __shfl_xor(d, off, 32);
            if (sl == t0 + j){ myd = d; mym = cm[j]; }
        }
    }

    float d16 = 0.f;
    for (int r = 0; r < KNB; ++r){
        float bv = myd; int bi = mym;
        #pragma unroll
        for (int off = 16; off; off >>= 1){
            float ov = __shfl_xor(bv, off, 32);
            int   oi = __shfl_xor(bi, off, 32);
            if (ov < bv || (ov == bv && oi < bi)){ bv = ov; bi = oi; }
        }
        if (sl == 0) idxf[((size_t)b * NPT + q) * KNB + r] = bi;
        if (mym == bi){ myd = INFINITY; mym = 0x7fffffff; }
        d16 = bv;
    }
    float b17 = myd;
    #pragma unroll
    for (int off = 16; off; off >>= 1) b17 = fminf(b17, __shfl_xor(b17, off, 32));
    int flag = (b17 - d16 < 1e-3f + 2e-4f * d16) ? 1 : 0;
    flag = __shfl(flag, 0, 32);
    if (!flag) return;

    const double* qvd = featT + ((size_t)b * NPT + q) * CH;
    double qrd[6];
    #pragma unroll
    for (int j = 0; j < 6; ++j) qrd[j] = qvd[sl + 32 * j];
    double mydd = INFINITY; int mymd = 0x7fffffff;
    for (int t = 0; t < KCAND; ++t){
        int m = cl[t];
        const double* cv = featT + ((size_t)b * NPT + m) * CH;
        double d = 0.;
        #pragma unroll
        for (int e = 0; e < 6; ++e){
            double dv = cv[sl + 32 * e] - qrd[e];
            d = fma(dv, dv, d);
        }
        #pragma unroll
        for (int off = 16; off; off >>= 1) d += __shfl_xor(d, off, 32);
        if (sl == t){ mydd = d; mymd = m; }
    }
    for (int r = 0; r < KNB; ++r){
        double bv = mydd; int bi = mymd;
        #pragma unroll
        for (int off = 16; off; off >>= 1){
            double ov = __shfl_xor(bv, off, 32);
            int    oi = __shfl_xor(bi, off, 32);
            if (ov < bv || (ov == bv && oi < bi)){ bv = ov; bi = oi; }
        }
        if (sl == 0) idxf[((size_t)b * NPT + q) * KNB + r] = bi;
        if (mymd == bi){ mydd = INFINITY; mymd = 0x7fffffff; }
    }
}

// ---------------- gather v2: coalesced rows + LDS-transposed hcat write; inline BN0 shift -------
__global__ __launch_bounds__(128) void k_gather2(
    const float* __restrict__ feat32, const float* __restrict__ g0,
    const float* __restrict__ b0, const double* __restrict__ s0sum,
    const double* __restrict__ s0sq, const int* __restrict__ idx,
    float* __restrict__ hcat)
{
    __shared__ float lt[192 * 33];
    __shared__ int il[32 * KNB];
    __shared__ float shl[CH];
    const int tid = threadIdx.x;
    const int n0  = blockIdx.x * 32;
    const int cg  = blockIdx.y;
    const int b   = blockIdx.z;

    for (int i = tid; i < 32 * KNB; i += 128)
        il[i] = idx[((size_t)b * NPT + n0) * KNB + i];
    for (int i = tid; i < CH; i += 128){
        double mean = s0sum[i] / NT64;
        double var  = s0sq[i] / NT64 - mean * mean;
        double sc   = (1.0 / sqrt(var + 1e-5)) * (double)g0[i];
        shl[i] = (float)((double)b0[i] - mean * sc);
    }
    __syncthreads();

    const int nl = tid >> 2, sub = tid & 3;
    const int n  = n0 + nl;
    const float* fbase = feat32 + (size_t)b * NPT * CH;
    const float* qr = fbase + (size_t)n * CH + cg * 96;

    float4 qv[6], mx[6];
    #pragma unroll
    for (int j = 0; j < 6; ++j){
        qv[j] = *reinterpret_cast<const float4*>(qr + (sub + 4 * j) * 4);
        mx[j] = make_float4(-INFINITY, -INFINITY, -INFINITY, -INFINITY);
    }

    #pragma unroll 4
    for (int k = 0; k < KNB; ++k){
        const float* cr = fbase + (size_t)il[nl * KNB + k] * CH + cg * 96;
        #pragma unroll
        for (int j = 0; j < 6; ++j){
            float4 v = *reinterpret_cast<const float4*>(cr + (sub + 4 * j) * 4);
            mx[j].x = fmaxf(mx[j].x, v.x - qv[j].x);
            mx[j].y = fmaxf(mx[j].y, v.y - qv[j].y);
            mx[j].z = fmaxf(mx[j].z, v.z - qv[j].z);
            mx[j].w = fmaxf(mx[j].w, v.w - qv[j].w);
        }
    }

    #pragma unroll
    for (int j = 0; j < 6; ++j){
        const int cb = (sub + 4 * j) * 4;
        float4 s4 = *reinterpret_cast<const float4*>(&shl[cg * 96 + cb]);
        float fi[4] = {qv[j].x + s4.x, qv[j].y + s4.y, qv[j].z + s4.z, qv[j].w + s4.w};
        float mm[4] = {mx[j].x, mx[j].y, mx[j].z, mx[j].w};
        #pragma unroll
        for (int e = 0; e < 4; ++e){
            int cl = cb + e;
            lt[(2 * cl) * 33 + nl]     = fi[e];
            lt[(2 * cl + 1) * 33 + nl] = mm[e];
        }
    }
    __syncthreads();

    const int rsub = tid >> 5;
    const int ni   = tid & 31;
    for (int r0 = 0; r0 < 192; r0 += 4){
        int row = r0 + rsub;
        int ch  = cg * 192 + row;
        hcat[((size_t)b * 2 * CH + ch) * NPT + n0 + ni] = lt[row * 33 + ni];
    }
}

// ---------------- mr-conv GEMM (K=384) + bias, with fused BN1-stat atomics ----------------------
__global__ __launch_bounds__(256) void k_gemm_mr(
    const float* __restrict__ in, const float* __restrict__ W, const float* __restrict__ bias,
    float* __restrict__ out, float* __restrict__ s1sum, float* __restrict__ s1sq)
{
    constexpr int KDIM = 2 * CH, OT = 8, NT = 4;
    __shared__ float wtT[KDIM][OT];
    __shared__ float redS[4][8], redQ[4][8];
    const int tid = threadIdx.x;
    const int o0  = blockIdx.y * OT;
    const int b   = blockIdx.z;
    const int n   = blockIdx.x * (256 * NT) + tid * NT;

    for (int lin = tid; lin < KDIM * OT; lin += 256){
        int c = lin >> 3, o = lin & 7;
        wtT[c][o] = W[(size_t)(o0 + o) * KDIM + c];
    }
    __syncthreads();

    float acc[OT][NT] = {};
    const float* ip = in + (size_t)b * KDIM * NPT + n;
    #pragma unroll 2
    for (int c = 0; c < KDIM; ++c){
        float4 x4 = *reinterpret_cast<const float4*>(ip + (size_t)c * NPT);
        float xv[NT] = {x4.x, x4.y, x4.z, x4.w};
        float4 w0 = *reinterpret_cast<const float4*>(&wtT[c][0]);
        float4 w1 = *reinterpret_cast<const float4*>(&wtT[c][4]);
        float wv[OT] = {w0.x, w0.y, w0.z, w0.w, w1.x, w1.y, w1.z, w1.w};
        #pragma unroll
        for (int oo = 0; oo < OT; ++oo)
            #pragma unroll
            for (int j = 0; j < NT; ++j)
                acc[oo][j] = fmaf(wv[oo], xv[j], acc[oo][j]);
    }

    float ps[OT], pq[OT];
    #pragma unroll
    for (int oo = 0; oo < OT; ++oo){
        size_t off = ((size_t)b * CH + o0 + oo) * NPT + n;
        float add = bias[o0 + oo];
        float vals[4];
        float s = 0.f, q = 0.f;
        #pragma unroll
        for (int j = 0; j < 4; ++j){
            vals[j] = acc[oo][j] + add;
            s += vals[j];
            q = fmaf(vals[j], vals[j], q);
        }
        ps[oo] = s; pq[oo] = q;
        float4 o4; o4.x = vals[0]; o4.y = vals[1]; o4.z = vals[2]; o4.w = vals[3];
        *reinterpret_cast<float4*>(out + off) = o4;
    }

    #pragma unroll
    for (int oo = 0; oo < OT; ++oo){
        #pragma unroll
        for (int off = 32; off; off >>= 1){
            ps[oo] += __shfl_xor(ps[oo], off);
            pq[oo] += __shfl_xor(pq[oo], off);
        }
    }
    const int wv = tid >> 6, lane = tid & 63;
    if (lane == 0){
        #pragma unroll
        for (int oo = 0; oo < OT; ++oo){ redS[wv][oo] = ps[oo]; redQ[wv][oo] = pq[oo]; }
    }
    __syncthreads();
    if (tid < 8){
        float s = redS[0][tid] + redS[1][tid] + redS[2][tid] + redS[3][tid];
        float q = redQ[0][tid] + redQ[1][tid] + redQ[2][tid] + redQ[3][tid];
        atomicAdd(&s1sum[o0 + tid], s);
        atomicAdd(&s1sq[o0 + tid], q);
    }
}

// ---------------- u = gelu(gelu(BN1(t2))), BN1 from sums; fused BN2-stat atomics ----------------
__global__ __launch_bounds__(256) void k_u(
    const float* __restrict__ in, const float* __restrict__ s1sum, const float* __restrict__ s1sq,
    const float* __restrict__ gm, const float* __restrict__ bm,
    float* __restrict__ out, float* __restrict__ s2sum, float* __restrict__ s2sq)
{
    __shared__ float redS[4], redQ[4];
    const int c = blockIdx.y, b = blockIdx.z;
    const int n = (blockIdx.x * 256 + threadIdx.x) * 4;
    const float invn = 1.0f / NTOT;
    float mean = s1sum[c] * invn;
    float var  = s1sq[c] * invn - mean * mean;
    float rstd = rsqrtf(var + 1e-5f);
    float s = rstd * gm[c], t = bm[c] - mean * s;

    size_t i = ((size_t)b * CH + c) * NPT + n;
    float4 v = *reinterpret_cast<const float4*>(in + i);
    float4 o;
    o.x = gelu_exact(gelu_exact(fmaf(v.x, s, t)));
    o.y = gelu_exact(gelu_exact(fmaf(v.y, s, t)));
    o.z = gelu_exact(gelu_exact(fmaf(v.z, s, t)));
    o.w = gelu_exact(gelu_exact(fmaf(v.w, s, t)));
    *reinterpret_cast<float4*>(out + i) = o;

    float ps = o.x + o.y + o.z + o.w;
    float pq = fmaf(o.x, o.x, fmaf(o.y, o.y, fmaf(o.z, o.z, o.w * o.w)));
    #pragma unroll
    for (int off = 32; off; off >>= 1){
        ps += __shfl_xor(ps, off);
        pq += __shfl_xor(pq, off);
    }
    const int wv = threadIdx.x >> 6, lane = threadIdx.x & 63;
    if (lane == 0){ redS[wv] = ps; redQ[wv] = pq; }
    __syncthreads();
    if (threadIdx.x == 0){
        atomicAdd(&s2sum[c], redS[0] + redS[1] + redS[2] + redS[3]);
        atomicAdd(&s2sq[c],  redQ[0] + redQ[1] + redQ[2] + redQ[3]);
    }
}

// ---------------- fc2 GEMM with BN2 (from sums) folded into input + residual --------------------
__global__ __launch_bounds__(256) void k_gemm_fc2(
    const float* __restrict__ in, const float* __restrict__ W,
    const float* __restrict__ s2sum, const float* __restrict__ s2sq,
    const float* __restrict__ g1, const float* __restrict__ b1,
    const float* __restrict__ resid, float* __restrict__ out)
{
    constexpr int KDIM = CH, OT = 8, NT = 4;
    __shared__ float wtT[KDIM][OT];
    __shared__ float scl[KDIM], shl[KDIM];
    const int tid = threadIdx.x;
    const int o0  = blockIdx.y * OT;
    const int b   = blockIdx.z;
    const int n   = blockIdx.x * (256 * NT) + tid * NT;

    for (int lin = tid; lin < KDIM * OT; lin += 256){
        int c = lin >> 3, o = lin & 7;
        wtT[c][o] = W[(size_t)(o0 + o) * KDIM + c];
    }
    const float invn = 1.0f / NTOT;
    for (int c = tid; c < KDIM; c += 256){
        float mean = s2sum[c] * invn;
        float var  = s2sq[c] * invn - mean * mean;
        float rstd = rsqrtf(var + 1e-5f);
        float s = rstd * g1[c];
        scl[c] = s;
        shl[c] = b1[c] - mean * s;
    }
    __syncthreads();

    float acc[OT][NT] = {};
    const float* ip = in + (size_t)b * KDIM * NPT + n;
    #pragma unroll 2
    for (int c = 0; c < KDIM; ++c){
        float4 x4 = *reinterpret_cast<const float4*>(ip + (size_t)c * NPT);
        float xv[NT];
        xv[0] = fmaf(x4.x, scl[c], shl[c]);
        xv[1] = fmaf(x4.y, scl[c], shl[c]);
        xv[2] = fmaf(x4.z, scl[c], shl[c]);
        xv[3] = fmaf(x4.w, scl[c], shl[c]);
        float4 w0 = *reinterpret_cast<const float4*>(&wtT[c][0]);
        float4 w1 = *reinterpret_cast<const float4*>(&wtT[c][4]);
        float wv[OT] = {w0.x, w0.y, w0.z, w0.w, w1.x, w1.y, w1.z, w1.w};
        #pragma unroll
        for (int oo = 0; oo < OT; ++oo)
            #pragma unroll
            for (int j = 0; j < NT; ++j)
                acc[oo][j] = fmaf(wv[oo], xv[j], acc[oo][j]);
    }

    #pragma unroll
    for (int oo = 0; oo < OT; ++oo){
        size_t off = ((size_t)b * CH + o0 + oo) * NPT + n;
        float4 r4 = *reinterpret_cast<const float4*>(resid + off);
        float4 o4;
        o4.x = acc[oo][0] + r4.x; o4.y = acc[oo][1] + r4.y;
        o4.z = acc[oo][2] + r4.z; o4.w = acc[oo][3] + r4.w;
        *reinterpret_cast<float4*>(out + off) = o4;
    }
}

extern "C" void kernel_launch(void* const* d_in, const int* in_sizes, int n_in,
                              void* d_out, int out_size, void* d_ws, size_t ws_size,
                              hipStream_t stream)
{
    const float* x    = (const float*)d_in[0];
    const float* w1   = (const float*)d_in[1];
    const float* w2   = (const float*)d_in[2];
    const float* wmr  = (const float*)d_in[3];
    const float* bmr  = (const float*)d_in[4];
    const float* g0   = (const float*)d_in[5];
    const float* b0   = (const float*)d_in[6];
    const float* gm   = (const float*)d_in[7];
    const float* bm   = (const float*)d_in[8];
    const float* g1   = (const float*)d_in[9];
    const float* b1   = (const float*)d_in[10];
    float* outp = (float*)d_out;

    const size_t BCN = (size_t)BSZ * CH * NPT;
    float*  A      = (float*)d_ws;                       // BCN f32: t2
    float*  Bb     = A + BCN;                            // BCN f32: featP (bf16) -> u
    unsigned short* featP = (unsigned short*)Bb;
    float*  Cc     = Bb + BCN;                           // 2*BCN f32: t1d (f64) -> hcat
    double* t1d    = (double*)Cc;
    double* featT  = (double*)(Cc + 2 * BCN);            // BCN f64
    float*  feat32 = (float*)(featT + BCN);              // BCN f32
    float*  sqv    = feat32 + BCN;                       // B*N
    int*    idxh   = (int*)(sqv + (size_t)BSZ * NPT);    // B*N*32
    int*    idxf   = idxh + (size_t)BSZ * NPT * KCAND;   // B*N*16
    float*  bnacc  = (float*)(idxf + (size_t)BSZ * NPT * KNB);  // 4*CH f32
    float *s1sum = bnacc, *s1sq = bnacc + CH, *s2sum = bnacc + 2 * CH, *s2sq = bnacc + 3 * CH;
    double* s0sum  = (double*)(bnacc + 4 * CH);          // CH f64
    double* s0sq   = s0sum + CH;                         // CH f64

    dim3 gg(NPT / 1024, CH / 8, BSZ);
    dim3 ge(NPT / 1024, CH, BSZ);

    // zero fp32 BN accumulators + f64 BN0 accumulators (contiguous)
    hipMemsetAsync(bnacc, 0, 4 * CH * sizeof(float) + 2 * CH * sizeof(double), stream);
    // fc1 (f64 accumulate) + fused BN0 stats
    k_fc1_f64<<<gg, 256, 0, stream>>>(x, w1, t1d, s0sum, s0sq);
    // fused transpose/scale (inline BN0 scale) -> featT + feat32 + featP + sqv
    k_feat<<<dim3(NPT / 32, BSZ), dim3(32, 8), 0, stream>>>(t1d, g0, s0sum, s0sq,
                                                            featT, feat32, featP, sqv);
    // kNN prefilter v12 (16 waves/block, m-eighths, 100% occupancy headroom)
    k_knn_mfma<<<dim3(2 * NPT / 64, BSZ), 1024, 0, stream>>>(featP, sqv, idxh);
    // fused refine v4 (2 q/wave, 32-candidate, certified f64 fallback)
    k_refine<<<dim3(NPT / 8, BSZ), 256, 0, stream>>>(feat32, featT, idxh, idxf);
    // gather (coalesced; inline BN0 shift; writes hcat over dead t1d)
    k_gather2<<<dim3(NPT / 32, 2, BSZ), 128, 0, stream>>>(feat32, g0, b0, s0sum, s0sq, idxf, Cc);
    // mr conv + bias + BN1-stat atomics
    k_gemm_mr<<<gg, 256, 0, stream>>>(Cc, wmr, bmr, A, s1sum, s1sq);
    // u = gelu(gelu(BN1(t2))) + BN2-stat atomics
    k_u<<<ge, 256, 0, stream>>>(A, s1sum, s1sq, gm, bm, Bb, s2sum, s2sq);
    // fc2 with BN2 folded + residual
    k_gemm_fc2<<<gg, 256, 0, stream>>>(Bb, w2, s2sum, s2sq, g1, b1, x, outp);
}

// Round 20
// 336.258 us; speedup vs baseline: 1.4424x; 1.1065x over previous
//
#include <hip/hip_runtime.h>
#include <hip/hip_bf16.h>
#include <math.h>

#define BSZ 4
#define NPT 4096
#define CH  192
#define KNB 16
#define KPH 16              // kept per half (top-16/half provably suffices)
#define KCAND (2 * KPH)     // 32 refine candidates
#define NTOT ((float)(BSZ * NPT))
#define NT64 ((double)(BSZ * NPT))

typedef short short8 __attribute__((ext_vector_type(8)));
typedef float f32x4  __attribute__((ext_vector_type(4)));

__device__ __forceinline__ float gelu_exact(float x){
    return 0.5f * x * (1.0f + erff(x * 0.70710678118654752440f));
}
__device__ __forceinline__ unsigned int umin_(unsigned int a, unsigned int b){ return a < b ? a : b; }
__device__ __forceinline__ unsigned int umax_(unsigned int a, unsigned int b){ return a < b ? b : a; }
__device__ __forceinline__ unsigned int umed3_(unsigned int a, unsigned int b, unsigned int c){
    unsigned int r;
    asm("v_med3_u32 %0, %1, %2, %3" : "=v"(r) : "v"(a), "v"(b), "v"(c));
    return r;
}
__device__ __forceinline__ unsigned short bf16rnd(float v){
    unsigned int bits = __builtin_bit_cast(unsigned int, v);
    return (unsigned short)((bits + 0x7fff + ((bits >> 16) & 1)) >> 16);
}

// ---------------- fc1 (f64 accumulate) -> f64 t1, with fused BN0-stat f64 atomics ---------------
__global__ __launch_bounds__(256) void k_fc1_f64(
    const float* __restrict__ in, const float* __restrict__ W, double* __restrict__ outd,
    double* __restrict__ s0sum, double* __restrict__ s0sq)
{
    constexpr int OT = 8, NT = 4;
    __shared__ float wtT[CH][OT];
    __shared__ double redS[4][8], redQ[4][8];
    const int tid = threadIdx.x;
    const int o0  = blockIdx.y * OT;
    const int b   = blockIdx.z;
    const int n   = blockIdx.x * (256 * NT) + tid * NT;

    for (int lin = tid; lin < CH * OT; lin += 256){
        int c = lin >> 3, o = lin & 7;
        wtT[c][o] = W[(size_t)(o0 + o) * CH + c];
    }
    __syncthreads();

    double acc[OT][NT] = {};
    const float* ip = in + (size_t)b * CH * NPT + n;
    for (int c = 0; c < CH; ++c){
        float4 x4 = *reinterpret_cast<const float4*>(ip + (size_t)c * NPT);
        double xv[NT] = {x4.x, x4.y, x4.z, x4.w};
        float4 w0 = *reinterpret_cast<const float4*>(&wtT[c][0]);
        float4 w1 = *reinterpret_cast<const float4*>(&wtT[c][4]);
        double wv[OT] = {w0.x, w0.y, w0.z, w0.w, w1.x, w1.y, w1.z, w1.w};
        #pragma unroll
        for (int oo = 0; oo < OT; ++oo)
            #pragma unroll
            for (int j = 0; j < NT; ++j)
                acc[oo][j] = fma(wv[oo], xv[j], acc[oo][j]);
    }

    double ps[OT], pq[OT];
    #pragma unroll
    for (int oo = 0; oo < OT; ++oo){
        size_t off = ((size_t)b * CH + o0 + oo) * NPT + n;
        double s = 0., q = 0.;
        #pragma unroll
        for (int j = 0; j < 4; ++j){
            double v = acc[oo][j];
            outd[off + j] = v;
            s += v; q = fma(v, v, q);
        }
        ps[oo] = s; pq[oo] = q;
    }

    #pragma unroll
    for (int oo = 0; oo < OT; ++oo){
        #pragma unroll
        for (int off = 32; off; off >>= 1){
            ps[oo] += __shfl_xor(ps[oo], off);
            pq[oo] += __shfl_xor(pq[oo], off);
        }
    }
    const int wv = tid >> 6, lane = tid & 63;
    if (lane == 0){
        #pragma unroll
        for (int oo = 0; oo < OT; ++oo){ redS[wv][oo] = ps[oo]; redQ[wv][oo] = pq[oo]; }
    }
    __syncthreads();
    if (tid < 8){
        double s = redS[0][tid] + redS[1][tid] + redS[2][tid] + redS[3][tid];
        double q = redQ[0][tid] + redQ[1][tid] + redQ[2][tid] + redQ[3][tid];
        atomicAdd(&s0sum[o0 + tid], s);
        atomicAdd(&s0sq[o0 + tid], q);
    }
}

// ---------------- fused: transpose+scale -> featT(f64), feat32, featP (MFMA-fragment bf16), sqv -
__global__ void k_feat(
    const double* __restrict__ t1d, const float* __restrict__ g0,
    const double* __restrict__ s0sum, const double* __restrict__ s0sq,
    double* __restrict__ featT, float* __restrict__ feat32,
    unsigned short* __restrict__ featP, float* __restrict__ sqv)
{
    __shared__ double tile[32][33];
    __shared__ float sqp[32][33];
    __shared__ double scdl[CH];
    const int n0 = blockIdx.x * 32, b = blockIdx.y;
    const int tx = threadIdx.x, ty = threadIdx.y;
    const int tid = ty * 32 + tx;
    float part[4] = {0.f, 0.f, 0.f, 0.f};
    unsigned short* fpb = featP + (size_t)b * NPT * CH;

    for (int i = tid; i < CH; i += 256){
        double mean = s0sum[i] / NT64;
        double var  = s0sq[i] / NT64 - mean * mean;
        scdl[i] = (1.0 / sqrt(var + 1e-5)) * (double)g0[i];
    }
    __syncthreads();

    for (int cc = 0; cc < CH / 32; ++cc){
        const int cbase = cc * 32;
        #pragma unroll
        for (int r = 0; r < 32; r += 8){
            int c = cbase + ty + r;
            tile[ty + r][tx] = t1d[((size_t)b * CH + c) * NPT + n0 + tx] * scdl[c];
        }
        __syncthreads();
        #pragma unroll
        for (int r = 0; r < 32; r += 8){
            int n = n0 + ty + r;
            int c = cbase + tx;
            double v = tile[tx][ty + r];
            size_t o = ((size_t)b * NPT + n) * CH + c;
            featT[o] = v;
            float f = (float)v;
            feat32[o] = f;
            part[r >> 3] = fmaf(f, f, part[r >> 3]);
        }
        if (tid < 128){
            const int t_ = tid >> 6;
            const int l  = tid & 63;
            const int r_ = l & 15, g_ = l >> 4;
            const int nl = t_ * 16 + r_;
            short8 pk;
            #pragma unroll
            for (int e = 0; e < 8; ++e)
                pk[e] = (short)bf16rnd((float)tile[g_ * 8 + e][nl]);
            const int tP = blockIdx.x * 2 + t_;
            *reinterpret_cast<short8*>(fpb + (size_t)(tP * 6 + cc) * 512 + l * 8) = pk;
        }
        __syncthreads();
    }
    #pragma unroll
    for (int j = 0; j < 4; ++j) sqp[ty + 8 * j][tx] = part[j];
    __syncthreads();
    if (ty == 0){
        float s = 0.f;
        #pragma unroll 8
        for (int k = 0; k < 32; ++k) s += sqp[tx][k];
        sqv[b * NPT + n0 + tx] = s;
    }
}

// ---------------- MFMA kNN prefilter v12: 1024 thr (16 waves), m-eighth waves -------------------
__global__ __launch_bounds__(1024, 8) void k_knn_mfma(
    const unsigned short* __restrict__ featP, const float* __restrict__ sqv,
    int* __restrict__ idxh)
{
    __shared__ unsigned int mlist[16][16][17];
    const int tid  = threadIdx.x;
    const int wv   = tid >> 6;
    const int lane = tid & 63;
    const int r = lane & 15, g = lane >> 4;
    const int b    = blockIdx.y;
    const int qt   = blockIdx.x >> 1;
    const int half = blockIdx.x & 1;
    const int qs = wv >> 2, me = wv & 3;
    const int tq   = qt * 4 + qs;
    const int tm0  = half * 128 + me * 32;
    const unsigned short* fp = featP + (size_t)b * NPT * CH;

    short8 bq0, bq1, bq2, bq3, bq4, bq5;
    {
        const unsigned short* qp = fp + (size_t)tq * 3072 + lane * 8;
        bq0 = *reinterpret_cast<const short8*>(qp);
        bq1 = *reinterpret_cast<const short8*>(qp + 512);
        bq2 = *reinterpret_cast<const short8*>(qp + 1024);
        bq3 = *reinterpret_cast<const short8*>(qp + 1536);
        bq4 = *reinterpret_cast<const short8*>(qp + 2048);
        bq5 = *reinterpret_cast<const short8*>(qp + 2560);
    }

    unsigned int Q[16];
    #pragma unroll
    for (int e = 0; e < 16; ++e) Q[e] = 0xFFFFFFFFu;

    const float* sq = sqv + b * NPT;
    const unsigned short* pa = fp + (size_t)tm0 * 3072 + lane * 8;

    for (int it = 0; it < 32; ++it){
        const unsigned short* p = pa + (size_t)it * 3072;
        short8 a0 = *reinterpret_cast<const short8*>(p);
        short8 a1 = *reinterpret_cast<const short8*>(p + 512);
        short8 a2 = *reinterpret_cast<const short8*>(p + 1024);
        short8 a3 = *reinterpret_cast<const short8*>(p + 1536);
        short8 a4 = *reinterpret_cast<const short8*>(p + 2048);
        short8 a5 = *reinterpret_cast<const short8*>(p + 2560);
        const int tm = tm0 + it;
        float4 s4 = *reinterpret_cast<const float4*>(sq + tm * 16 + 4 * g);

        f32x4 acc = {0.f, 0.f, 0.f, 0.f};
        acc = __builtin_amdgcn_mfma_f32_16x16x32_bf16(a0, bq0, acc, 0, 0, 0);
        acc = __builtin_amdgcn_mfma_f32_16x16x32_bf16(a1, bq1, acc, 0, 0, 0);
        acc = __builtin_amdgcn_mfma_f32_16x16x32_bf16(a2, bq2, acc, 0, 0, 0);
        acc = __builtin_amdgcn_mfma_f32_16x16x32_bf16(a3, bq3, acc, 0, 0, 0);
        acc = __builtin_amdgcn_mfma_f32_16x16x32_bf16(a4, bq4, acc, 0, 0, 0);
        acc = __builtin_amdgcn_mfma_f32_16x16x32_bf16(a5, bq5, acc, 0, 0, 0);

        const int m0 = tm * 16 + 4 * g;
        float sa[4] = {s4.x, s4.y, s4.z, s4.w};
        #pragma unroll
        for (int u = 0; u < 4; ++u){
            float d = fmaxf(fmaf(-2.0f, acc[u], sa[u]), 0.0f);
            unsigned int k = (__builtin_bit_cast(unsigned int, d) & 0xFFFFF000u)
                           | (unsigned int)(m0 + u);
            #pragma unroll
            for (int pz = 0; pz < 8; ++pz){
                unsigned int a = Q[2 * pz], bv = Q[2 * pz + 1];
                Q[2 * pz]     = umin_(a, k);
                Q[2 * pz + 1] = umed3_(a, bv, k);
                k             = umax_(bv, k);
            }
        }
    }

    #pragma unroll 1
    for (int rd = 0; rd < 16; ++rd){
        unsigned int v = Q[0];
        v = umin_(v, (unsigned int)__shfl_xor((int)v, 16));
        v = umin_(v, (unsigned int)__shfl_xor((int)v, 32));
        bool win = (Q[0] == v);
        if (win){
            #pragma unroll
            for (int e = 0; e < 15; ++e) Q[e] = Q[e + 1];
            Q[15] = 0xFFFFFFFFu;
        }
        if (g == 0) mlist[wv][r][rd] = v;
    }
    if (g == 0) mlist[wv][r][16] = 0xFFFFFFFFu;
    __syncthreads();

    if (tid < 64){
        const int qq = tid;
        const int q2 = qq >> 4, rr = qq & 15;
        int i0 = 0, i1 = 0, i2 = 0, i3 = 0;
        int* op = idxh + ((size_t)(b * NPT + qt * 64 + qq) * 2 + half) * KPH;
        for (int rd = 0; rd < KPH; ++rd){
            unsigned int k0 = mlist[q2 * 4 + 0][rr][i0];
            unsigned int k1 = mlist[q2 * 4 + 1][rr][i1];
            unsigned int k2 = mlist[q2 * 4 + 2][rr][i2];
            unsigned int k3 = mlist[q2 * 4 + 3][rr][i3];
            unsigned int mm = umin_(umin_(k0, k1), umin_(k2, k3));
            op[rd] = (int)(mm & 0xFFFu);
            i0 += (k0 == mm); i1 += (k1 == mm); i2 += (k2 == mm); i3 += (k3 == mm);
        }
    }
}

// ---------------- fused refine v4: 2 queries/wave, 32-lane groups, certified f64 fallback -------
__global__ __launch_bounds__(256) void k_refine(
    const float* __restrict__ feat32, const double* __restrict__ featT,
    const int* __restrict__ idxh, int* __restrict__ idxf)
{
    const int q = blockIdx.x * 8 + (threadIdx.x >> 5);
    const int b = blockIdx.y;
    const int sl = threadIdx.x & 31;
    const int* cl = idxh + ((size_t)b * NPT + q) * KCAND;
    const float* qv = feat32 + ((size_t)b * NPT + q) * CH;
    float qr[6];
    #pragma unroll
    for (int j = 0; j < 6; ++j) qr[j] = qv[sl + 32 * j];

    float myd = INFINITY; int mym = 0x7fffffff;
    #pragma unroll
    for (int t0 = 0; t0 < KCAND; t0 += 8){
        float pd[8]; int cm[8];
        #pragma unroll
        for (int j = 0; j < 8; ++j){
            int m = cl[t0 + j];
            cm[j] = m;
            const float* cv = feat32 + ((size_t)b * NPT + m) * CH;
            float d = 0.f;
            #pragma unroll
            for (int e = 0; e < 6; ++e){
                float dv = cv[sl + 32 * e] - qr[e];
                d = fmaf(dv, dv, d);
            }
            pd[j] = d;
        }
        #pragma unroll
        for (int j = 0; j < 8; ++j){
            float d = pd[j];
            #pragma unroll
            for (int off = 16; off; off >>= 1) d += __shfl_xor(d, off, 32);
            if (sl == t0 + j){ myd = d; mym = cm[j]; }
        }
    }

    float d16 = 0.f;
    for (int r = 0; r < KNB; ++r){
        float bv = myd; int bi = mym;
        #pragma unroll
        for (int off = 16; off; off >>= 1){
            float ov = __shfl_xor(bv, off, 32);
            int   oi = __shfl_xor(bi, off, 32);
            if (ov < bv || (ov == bv && oi < bi)){ bv = ov; bi = oi; }
        }
        if (sl == 0) idxf[((size_t)b * NPT + q) * KNB + r] = bi;
        if (mym == bi){ myd = INFINITY; mym = 0x7fffffff; }
        d16 = bv;
    }
    float b17 = myd;
    #pragma unroll
    for (int off = 16; off; off >>= 1) b17 = fminf(b17, __shfl_xor(b17, off, 32));
    int flag = (b17 - d16 < 1e-3f + 2e-4f * d16) ? 1 : 0;
    flag = __shfl(flag, 0, 32);
    if (!flag) return;

    const double* qvd = featT + ((size_t)b * NPT + q) * CH;
    double qrd[6];
    #pragma unroll
    for (int j = 0; j < 6; ++j) qrd[j] = qvd[sl + 32 * j];
    double mydd = INFINITY; int mymd = 0x7fffffff;
    for (int t = 0; t < KCAND; ++t){
        int m = cl[t];
        const double* cv = featT + ((size_t)b * NPT + m) * CH;
        double d = 0.;
        #pragma unroll
        for (int e = 0; e < 6; ++e){
            double dv = cv[sl + 32 * e] - qrd[e];
            d = fma(dv, dv, d);
        }
        #pragma unroll
        for (int off = 16; off; off >>= 1) d += __shfl_xor(d, off, 32);
        if (sl == t){ mydd = d; mymd = m; }
    }
    for (int r = 0; r < KNB; ++r){
        double bv = mydd; int bi = mymd;
        #pragma unroll
        for (int off = 16; off; off >>= 1){
            double ov = __shfl_xor(bv, off, 32);
            int    oi = __shfl_xor(bi, off, 32);
            if (ov < bv || (ov == bv && oi < bi)){ bv = ov; bi = oi; }
        }
        if (sl == 0) idxf[((size_t)b * NPT + q) * KNB + r] = bi;
        if (mymd == bi){ mydd = INFINITY; mymd = 0x7fffffff; }
    }
}

// ---------------- gather v3: coalesced rows, inline BN0 shift, emits bf16 MFMA fragments --------
// grid (NPT/32, 2, BSZ): cg covers interleaved channels cg*192..cg*192+191 = ks slots cg*6..cg*6+5
__global__ __launch_bounds__(128) void k_gather2(
    const float* __restrict__ feat32, const float* __restrict__ g0,
    const float* __restrict__ b0, const double* __restrict__ s0sum,
    const double* __restrict__ s0sq, const int* __restrict__ idx,
    unsigned short* __restrict__ hfrag)
{
    __shared__ float lt[192 * 33];
    __shared__ int il[32 * KNB];
    __shared__ float shl[CH];
    const int tid = threadIdx.x;
    const int n0  = blockIdx.x * 32;
    const int cg  = blockIdx.y;
    const int b   = blockIdx.z;

    for (int i = tid; i < 32 * KNB; i += 128)
        il[i] = idx[((size_t)b * NPT + n0) * KNB + i];
    for (int i = tid; i < CH; i += 128){
        double mean = s0sum[i] / NT64;
        double var  = s0sq[i] / NT64 - mean * mean;
        double sc   = (1.0 / sqrt(var + 1e-5)) * (double)g0[i];
        shl[i] = (float)((double)b0[i] - mean * sc);
    }
    __syncthreads();

    const int nl = tid >> 2, sub = tid & 3;
    const int n  = n0 + nl;
    const float* fbase = feat32 + (size_t)b * NPT * CH;
    const float* qr = fbase + (size_t)n * CH + cg * 96;

    float4 qv[6], mx[6];
    #pragma unroll
    for (int j = 0; j < 6; ++j){
        qv[j] = *reinterpret_cast<const float4*>(qr + (sub + 4 * j) * 4);
        mx[j] = make_float4(-INFINITY, -INFINITY, -INFINITY, -INFINITY);
    }

    #pragma unroll 4
    for (int k = 0; k < KNB; ++k){
        const float* cr = fbase + (size_t)il[nl * KNB + k] * CH + cg * 96;
        #pragma unroll
        for (int j = 0; j < 6; ++j){
            float4 v = *reinterpret_cast<const float4*>(cr + (sub + 4 * j) * 4);
            mx[j].x = fmaxf(mx[j].x, v.x - qv[j].x);
            mx[j].y = fmaxf(mx[j].y, v.y - qv[j].y);
            mx[j].z = fmaxf(mx[j].z, v.z - qv[j].z);
            mx[j].w = fmaxf(mx[j].w, v.w - qv[j].w);
        }
    }

    #pragma unroll
    for (int j = 0; j < 6; ++j){
        const int cb = (sub + 4 * j) * 4;      // local feature ch base (0..95)
        float4 s4 = *reinterpret_cast<const float4*>(&shl[cg * 96 + cb]);
        float fi[4] = {qv[j].x + s4.x, qv[j].y + s4.y, qv[j].z + s4.z, qv[j].w + s4.w};
        float mm[4] = {mx[j].x, mx[j].y, mx[j].z, mx[j].w};
        #pragma unroll
        for (int e = 0; e < 4; ++e){
            int cl = cb + e;                   // interleaved rows 2*cl, 2*cl+1 (local 0..191)
            lt[(2 * cl) * 33 + nl]     = fi[e];
            lt[(2 * cl + 1) * 33 + nl] = mm[e];
        }
    }
    __syncthreads();

    // emit bf16 MFMA fragments for the 6 ks slots this block owns
    const int jt0 = (b * NPT + n0) >> 4;
    const int wvv = tid >> 6;                  // 0..1
    const int l   = tid & 63;
    for (int p = wvv; p < 12; p += 2){
        const int t_ = p & 1, ksl = p >> 1;    // n-subtile, local ks slot
        short8 pk;
        #pragma unroll
        for (int e = 0; e < 8; ++e){
            int ic = ksl * 32 + (l >> 4) * 8 + e;      // local interleaved ch (0..191)
            pk[e] = (short)bf16rnd(lt[ic * 33 + t_ * 16 + (l & 15)]);
        }
        *reinterpret_cast<short8*>(
            &hfrag[((size_t)(jt0 + t_) * 12 + cg * 6 + ksl) * 512 + l * 8]) = pk;
    }
}

// ---------------- w_mr -> bf16 MFMA fragments ----------------------------------------------------
__global__ __launch_bounds__(64) void k_wprep(
    const float* __restrict__ wmr, unsigned short* __restrict__ wfrag)
{
    const int ot = blockIdx.x, ks = blockIdx.y, l = threadIdx.x;
    short8 pk;
    #pragma unroll
    for (int e = 0; e < 8; ++e)
        pk[e] = (short)bf16rnd(wmr[(size_t)(ot * 16 + (l & 15)) * (2 * CH) + ks * 32 + (l >> 4) * 8 + e]);
    *reinterpret_cast<short8*>(&wfrag[((size_t)ot * 12 + ks) * 512 + l * 8]) = pk;
}

// ---------------- mr-conv GEMM via MFMA (bf16 fragments), bias + fused BN1 stats ----------------
// grid (BSZ*NPT/64), 256 thr (4 waves; wave wv owns n-subtile wv of the 64-col block).
__global__ __launch_bounds__(256) void k_gemm_mr(
    const unsigned short* __restrict__ hfrag, const unsigned short* __restrict__ wfrag,
    const float* __restrict__ bias, float* __restrict__ out,
    float* __restrict__ s1sum, float* __restrict__ s1sq)
{
    __shared__ unsigned short hl[4 * 12 * 512];    // 48 KB
    __shared__ unsigned short wl[12 * 512];        // 12 KB
    __shared__ float sstat[2 * CH];                // 1.5 KB
    const int tid = threadIdx.x;
    const int wv = tid >> 6, lane = tid & 63;
    const int g = lane >> 4;
    const int j0 = blockIdx.x * 64;
    const int b  = j0 >> 12;                       // NPT = 4096
    const int n0 = j0 & (NPT - 1);

    const unsigned short* hsrc = hfrag + (size_t)(j0 >> 4) * 12 * 512;
    for (int i = tid; i < 3072; i += 256)
        *reinterpret_cast<short8*>(&hl[i * 8]) = *reinterpret_cast<const short8*>(&hsrc[i * 8]);
    for (int i = tid; i < 2 * CH; i += 256) sstat[i] = 0.f;
    __syncthreads();

    for (int ot = 0; ot < 12; ++ot){
        for (int i = tid; i < 768; i += 256)
            *reinterpret_cast<short8*>(&wl[i * 8]) =
                *reinterpret_cast<const short8*>(&wfrag[((size_t)ot * 12) * 512 + i * 8]);
        __syncthreads();

        f32x4 acc = {0.f, 0.f, 0.f, 0.f};
        #pragma unroll
        for (int ks = 0; ks < 12; ++ks){
            short8 a = *reinterpret_cast<const short8*>(&wl[ks * 512 + lane * 8]);
            short8 h = *reinterpret_cast<const short8*>(&hl[(wv * 12 + ks) * 512 + lane * 8]);
            acc = __builtin_amdgcn_mfma_f32_16x16x32_bf16(a, h, acc, 0, 0, 0);
        }

        #pragma unroll
        for (int u = 0; u < 4; ++u){
            const int row = ot * 16 + 4 * g + u;
            float val = acc[u] + bias[row];
            out[((size_t)b * CH + row) * NPT + n0 + wv * 16 + (lane & 15)] = val;
            float s = val, q = val * val;
            #pragma unroll
            for (int off = 1; off < 16; off <<= 1){
                s += __shfl_xor(s, off, 16);
                q += __shfl_xor(q, off, 16);
            }
            if ((lane & 15) == 0){
                atomicAdd(&sstat[row], s);
                atomicAdd(&sstat[CH + row], q);
            }
        }
        __syncthreads();
    }

    if (tid < CH){
        atomicAdd(&s1sum[tid], sstat[tid]);
        atomicAdd(&s1sq[tid],  sstat[CH + tid]);
    }
}

// ---------------- u = gelu(gelu(BN1(t2))), BN1 from sums; fused BN2-stat atomics ----------------
__global__ __launch_bounds__(256) void k_u(
    const float* __restrict__ in, const float* __restrict__ s1sum, const float* __restrict__ s1sq,
    const float* __restrict__ gm, const float* __restrict__ bm,
    float* __restrict__ out, float* __restrict__ s2sum, float* __restrict__ s2sq)
{
    __shared__ float redS[4], redQ[4];
    const int c = blockIdx.y, b = blockIdx.z;
    const int n = (blockIdx.x * 256 + threadIdx.x) * 4;
    const float invn = 1.0f / NTOT;
    float mean = s1sum[c] * invn;
    float var  = s1sq[c] * invn - mean * mean;
    float rstd = rsqrtf(var + 1e-5f);
    float s = rstd * gm[c], t = bm[c] - mean * s;

    size_t i = ((size_t)b * CH + c) * NPT + n;
    float4 v = *reinterpret_cast<const float4*>(in + i);
    float4 o;
    o.x = gelu_exact(gelu_exact(fmaf(v.x, s, t)));
    o.y = gelu_exact(gelu_exact(fmaf(v.y, s, t)));
    o.z = gelu_exact(gelu_exact(fmaf(v.z, s, t)));
    o.w = gelu_exact(gelu_exact(fmaf(v.w, s, t)));
    *reinterpret_cast<float4*>(out + i) = o;

    float ps = o.x + o.y + o.z + o.w;
    float pq = fmaf(o.x, o.x, fmaf(o.y, o.y, fmaf(o.z, o.z, o.w * o.w)));
    #pragma unroll
    for (int off = 32; off; off >>= 1){
        ps += __shfl_xor(ps, off);
        pq += __shfl_xor(pq, off);
    }
    const int wv = threadIdx.x >> 6, lane = threadIdx.x & 63;
    if (lane == 0){ redS[wv] = ps; redQ[wv] = pq; }
    __syncthreads();
    if (threadIdx.x == 0){
        atomicAdd(&s2sum[c], redS[0] + redS[1] + redS[2] + redS[3]);
        atomicAdd(&s2sq[c],  redQ[0] + redQ[1] + redQ[2] + redQ[3]);
    }
}

// ---------------- fc2 GEMM with BN2 (from sums) folded into input + residual --------------------
__global__ __launch_bounds__(256) void k_gemm_fc2(
    const float* __restrict__ in, const float* __restrict__ W,
    const float* __restrict__ s2sum, const float* __restrict__ s2sq,
    const float* __restrict__ g1, const float* __restrict__ b1,
    const float* __restrict__ resid, float* __restrict__ out)
{
    constexpr int KDIM = CH, OT = 8, NT = 4;
    __shared__ float wtT[KDIM][OT];
    __shared__ float scl[KDIM], shl[KDIM];
    const int tid = threadIdx.x;
    const int o0  = blockIdx.y * OT;
    const int b   = blockIdx.z;
    const int n   = blockIdx.x * (256 * NT) + tid * NT;

    for (int lin = tid; lin < KDIM * OT; lin += 256){
        int c = lin >> 3, o = lin & 7;
        wtT[c][o] = W[(size_t)(o0 + o) * KDIM + c];
    }
    const float invn = 1.0f / NTOT;
    for (int c = tid; c < KDIM; c += 256){
        float mean = s2sum[c] * invn;
        float var  = s2sq[c] * invn - mean * mean;
        float rstd = rsqrtf(var + 1e-5f);
        float s = rstd * g1[c];
        scl[c] = s;
        shl[c] = b1[c] - mean * s;
    }
    __syncthreads();

    float acc[OT][NT] = {};
    const float* ip = in + (size_t)b * KDIM * NPT + n;
    #pragma unroll 2
    for (int c = 0; c < KDIM; ++c){
        float4 x4 = *reinterpret_cast<const float4*>(ip + (size_t)c * NPT);
        float xv[NT];
        xv[0] = fmaf(x4.x, scl[c], shl[c]);
        xv[1] = fmaf(x4.y, scl[c], shl[c]);
        xv[2] = fmaf(x4.z, scl[c], shl[c]);
        xv[3] = fmaf(x4.w, scl[c], shl[c]);
        float4 w0 = *reinterpret_cast<const float4*>(&wtT[c][0]);
        float4 w1 = *reinterpret_cast<const float4*>(&wtT[c][4]);
        float wv[OT] = {w0.x, w0.y, w0.z, w0.w, w1.x, w1.y, w1.z, w1.w};
        #pragma unroll
        for (int oo = 0; oo < OT; ++oo)
            #pragma unroll
            for (int j = 0; j < NT; ++j)
                acc[oo][j] = fmaf(wv[oo], xv[j], acc[oo][j]);
    }

    #pragma unroll
    for (int oo = 0; oo < OT; ++oo){
        size_t off = ((size_t)b * CH + o0 + oo) * NPT + n;
        float4 r4 = *reinterpret_cast<const float4*>(resid + off);
        float4 o4;
        o4.x = acc[oo][0] + r4.x; o4.y = acc[oo][1] + r4.y;
        o4.z = acc[oo][2] + r4.z; o4.w = acc[oo][3] + r4.w;
        *reinterpret_cast<float4*>(out + off) = o4;
    }
}

extern "C" void kernel_launch(void* const* d_in, const int* in_sizes, int n_in,
                              void* d_out, int out_size, void* d_ws, size_t ws_size,
                              hipStream_t stream)
{
    const float* x    = (const float*)d_in[0];
    const float* w1   = (const float*)d_in[1];
    const float* w2   = (const float*)d_in[2];
    const float* wmr  = (const float*)d_in[3];
    const float* bmr  = (const float*)d_in[4];
    const float* g0   = (const float*)d_in[5];
    const float* b0   = (const float*)d_in[6];
    const float* gm   = (const float*)d_in[7];
    const float* bm   = (const float*)d_in[8];
    const float* g1   = (const float*)d_in[9];
    const float* b1   = (const float*)d_in[10];
    float* outp = (float*)d_out;

    const size_t BCN = (size_t)BSZ * CH * NPT;
    float*  A      = (float*)d_ws;                       // BCN f32: t2
    float*  Bb     = A + BCN;                            // BCN f32: featP (bf16) -> u
    unsigned short* featP = (unsigned short*)Bb;
    float*  Cc     = Bb + BCN;                           // 2*BCN f32: t1d (f64) -> hfrag (bf16)
    double* t1d    = (double*)Cc;
    unsigned short* hfrag = (unsigned short*)Cc;         // 16384*384 bf16 = 12.6 MB (t1d dead)
    double* featT  = (double*)(Cc + 2 * BCN);            // BCN f64
    float*  feat32 = (float*)(featT + BCN);              // BCN f32
    float*  sqv    = feat32 + BCN;                       // B*N
    int*    idxh   = (int*)(sqv + (size_t)BSZ * NPT);    // B*N*32
    int*    idxf   = idxh + (size_t)BSZ * NPT * KCAND;   // B*N*16
    float*  bnacc  = (float*)(idxf + (size_t)BSZ * NPT * KNB);  // 4*CH f32
    float *s1sum = bnacc, *s1sq = bnacc + CH, *s2sum = bnacc + 2 * CH, *s2sq = bnacc + 3 * CH;
    double* s0sum  = (double*)(bnacc + 4 * CH);          // CH f64
    double* s0sq   = s0sum + CH;                         // CH f64
    unsigned short* wfrag = (unsigned short*)(s0sq + CH); // 12*12*512 bf16 = 147 KB

    dim3 gg(NPT / 1024, CH / 8, BSZ);
    dim3 ge(NPT / 1024, CH, BSZ);

    hipMemsetAsync(bnacc, 0, 4 * CH * sizeof(float) + 2 * CH * sizeof(double), stream);
    // w_mr -> bf16 fragments (tiny)
    k_wprep<<<dim3(12, 12), 64, 0, stream>>>(wmr, wfrag);
    // fc1 (f64 accumulate) + fused BN0 stats
    k_fc1_f64<<<gg, 256, 0, stream>>>(x, w1, t1d, s0sum, s0sq);
    // fused transpose/scale (inline BN0 scale) -> featT + feat32 + featP + sqv
    k_feat<<<dim3(NPT / 32, BSZ), dim3(32, 8), 0, stream>>>(t1d, g0, s0sum, s0sq,
                                                            featT, feat32, featP, sqv);
    // kNN prefilter v12 (16 waves/block)
    k_knn_mfma<<<dim3(2 * NPT / 64, BSZ), 1024, 0, stream>>>(featP, sqv, idxh);
    // fused refine v4 (certified f64 fallback)
    k_refine<<<dim3(NPT / 8, BSZ), 256, 0, stream>>>(feat32, featT, idxh, idxf);
    // gather v3: inline BN0 shift, emits bf16 fragments (over dead t1d)
    k_gather2<<<dim3(NPT / 32, 2, BSZ), 128, 0, stream>>>(feat32, g0, b0, s0sum, s0sq, idxf, hfrag);
    // mr conv via MFMA + bias + BN1-stat atomics
    k_gemm_mr<<<dim3(BSZ * NPT / 64), 256, 0, stream>>>(hfrag, wfrag, bmr, A, s1sum, s1sq);
    // u = gelu(gelu(BN1(t2))) + BN2-stat atomics
    k_u<<<ge, 256, 0, stream>>>(A, s1sum, s1sq, gm, bm, Bb, s2sum, s2sq);
    // fc2 with BN2 folded + residual
    k_gemm_fc2<<<gg, 256, 0, stream>>>(Bb, w2, s2sum, s2sq, g1, b1, x, outp);
}

// Round 21
// 333.381 us; speedup vs baseline: 1.4548x; 1.0086x over previous
//
#include <hip/hip_runtime.h>
#include <hip/hip_bf16.h>
#include <math.h>

#define BSZ 4
#define NPT 4096
#define CH  192
#define KNB 16
#define KPH 16              // kept per half (top-16/half provably suffices)
#define KCAND (2 * KPH)     // 32 refine candidates
#define NTOT ((float)(BSZ * NPT))
#define NT64 ((double)(BSZ * NPT))

typedef short short8 __attribute__((ext_vector_type(8)));
typedef float f32x4  __attribute__((ext_vector_type(4)));

__device__ __forceinline__ float gelu_exact(float x){
    return 0.5f * x * (1.0f + erff(x * 0.70710678118654752440f));
}
__device__ __forceinline__ unsigned int umin_(unsigned int a, unsigned int b){ return a < b ? a : b; }
__device__ __forceinline__ unsigned int umax_(unsigned int a, unsigned int b){ return a < b ? b : a; }
__device__ __forceinline__ unsigned int umed3_(unsigned int a, unsigned int b, unsigned int c){
    unsigned int r;
    asm("v_med3_u32 %0, %1, %2, %3" : "=v"(r) : "v"(a), "v"(b), "v"(c));
    return r;
}
__device__ __forceinline__ unsigned short bf16rnd(float v){
    unsigned int bits = __builtin_bit_cast(unsigned int, v);
    return (unsigned short)((bits + 0x7fff + ((bits >> 16) & 1)) >> 16);
}

// ---------------- fc1 (f64 accumulate) -> f64 t1, with fused BN0-stat f64 atomics ---------------
__global__ __launch_bounds__(256) void k_fc1_f64(
    const float* __restrict__ in, const float* __restrict__ W, double* __restrict__ outd,
    double* __restrict__ s0sum, double* __restrict__ s0sq)
{
    constexpr int OT = 8, NT = 4;
    __shared__ float wtT[CH][OT];
    __shared__ double redS[4][8], redQ[4][8];
    const int tid = threadIdx.x;
    const int o0  = blockIdx.y * OT;
    const int b   = blockIdx.z;
    const int n   = blockIdx.x * (256 * NT) + tid * NT;

    for (int lin = tid; lin < CH * OT; lin += 256){
        int c = lin >> 3, o = lin & 7;
        wtT[c][o] = W[(size_t)(o0 + o) * CH + c];
    }
    __syncthreads();

    double acc[OT][NT] = {};
    const float* ip = in + (size_t)b * CH * NPT + n;
    for (int c = 0; c < CH; ++c){
        float4 x4 = *reinterpret_cast<const float4*>(ip + (size_t)c * NPT);
        double xv[NT] = {x4.x, x4.y, x4.z, x4.w};
        float4 w0 = *reinterpret_cast<const float4*>(&wtT[c][0]);
        float4 w1 = *reinterpret_cast<const float4*>(&wtT[c][4]);
        double wv[OT] = {w0.x, w0.y, w0.z, w0.w, w1.x, w1.y, w1.z, w1.w};
        #pragma unroll
        for (int oo = 0; oo < OT; ++oo)
            #pragma unroll
            for (int j = 0; j < NT; ++j)
                acc[oo][j] = fma(wv[oo], xv[j], acc[oo][j]);
    }

    double ps[OT], pq[OT];
    #pragma unroll
    for (int oo = 0; oo < OT; ++oo){
        size_t off = ((size_t)b * CH + o0 + oo) * NPT + n;
        double s = 0., q = 0.;
        #pragma unroll
        for (int j = 0; j < 4; ++j){
            double v = acc[oo][j];
            outd[off + j] = v;
            s += v; q = fma(v, v, q);
        }
        ps[oo] = s; pq[oo] = q;
    }

    #pragma unroll
    for (int oo = 0; oo < OT; ++oo){
        #pragma unroll
        for (int off = 32; off; off >>= 1){
            ps[oo] += __shfl_xor(ps[oo], off);
            pq[oo] += __shfl_xor(pq[oo], off);
        }
    }
    const int wv = tid >> 6, lane = tid & 63;
    if (lane == 0){
        #pragma unroll
        for (int oo = 0; oo < OT; ++oo){ redS[wv][oo] = ps[oo]; redQ[wv][oo] = pq[oo]; }
    }
    __syncthreads();
    if (tid < 8){
        double s = redS[0][tid] + redS[1][tid] + redS[2][tid] + redS[3][tid];
        double q = redQ[0][tid] + redQ[1][tid] + redQ[2][tid] + redQ[3][tid];
        atomicAdd(&s0sum[o0 + tid], s);
        atomicAdd(&s0sq[o0 + tid], q);
    }
}

// ---------------- fused: transpose+scale -> featT(f64), feat32, featP (MFMA-fragment bf16), sqv -
__global__ void k_feat(
    const double* __restrict__ t1d, const float* __restrict__ g0,
    const double* __restrict__ s0sum, const double* __restrict__ s0sq,
    double* __restrict__ featT, float* __restrict__ feat32,
    unsigned short* __restrict__ featP, float* __restrict__ sqv)
{
    __shared__ double tile[32][33];
    __shared__ float sqp[32][33];
    __shared__ double scdl[CH];
    const int n0 = blockIdx.x * 32, b = blockIdx.y;
    const int tx = threadIdx.x, ty = threadIdx.y;
    const int tid = ty * 32 + tx;
    float part[4] = {0.f, 0.f, 0.f, 0.f};
    unsigned short* fpb = featP + (size_t)b * NPT * CH;

    for (int i = tid; i < CH; i += 256){
        double mean = s0sum[i] / NT64;
        double var  = s0sq[i] / NT64 - mean * mean;
        scdl[i] = (1.0 / sqrt(var + 1e-5)) * (double)g0[i];
    }
    __syncthreads();

    for (int cc = 0; cc < CH / 32; ++cc){
        const int cbase = cc * 32;
        #pragma unroll
        for (int r = 0; r < 32; r += 8){
            int c = cbase + ty + r;
            tile[ty + r][tx] = t1d[((size_t)b * CH + c) * NPT + n0 + tx] * scdl[c];
        }
        __syncthreads();
        #pragma unroll
        for (int r = 0; r < 32; r += 8){
            int n = n0 + ty + r;
            int c = cbase + tx;
            double v = tile[tx][ty + r];
            size_t o = ((size_t)b * NPT + n) * CH + c;
            featT[o] = v;
            float f = (float)v;
            feat32[o] = f;
            part[r >> 3] = fmaf(f, f, part[r >> 3]);
        }
        if (tid < 128){
            const int t_ = tid >> 6;
            const int l  = tid & 63;
            const int r_ = l & 15, g_ = l >> 4;
            const int nl = t_ * 16 + r_;
            short8 pk;
            #pragma unroll
            for (int e = 0; e < 8; ++e)
                pk[e] = (short)bf16rnd((float)tile[g_ * 8 + e][nl]);
            const int tP = blockIdx.x * 2 + t_;
            *reinterpret_cast<short8*>(fpb + (size_t)(tP * 6 + cc) * 512 + l * 8) = pk;
        }
        __syncthreads();
    }
    #pragma unroll
    for (int j = 0; j < 4; ++j) sqp[ty + 8 * j][tx] = part[j];
    __syncthreads();
    if (ty == 0){
        float s = 0.f;
        #pragma unroll 8
        for (int k = 0; k < 32; ++k) s += sqp[tx][k];
        sqv[b * NPT + n0 + tx] = s;
    }
}

// ---------------- MFMA kNN prefilter v12: 1024 thr (16 waves), m-eighth waves -------------------
__global__ __launch_bounds__(1024, 8) void k_knn_mfma(
    const unsigned short* __restrict__ featP, const float* __restrict__ sqv,
    int* __restrict__ idxh)
{
    __shared__ unsigned int mlist[16][16][17];
    const int tid  = threadIdx.x;
    const int wv   = tid >> 6;
    const int lane = tid & 63;
    const int r = lane & 15, g = lane >> 4;
    const int b    = blockIdx.y;
    const int qt   = blockIdx.x >> 1;
    const int half = blockIdx.x & 1;
    const int qs = wv >> 2, me = wv & 3;
    const int tq   = qt * 4 + qs;
    const int tm0  = half * 128 + me * 32;
    const unsigned short* fp = featP + (size_t)b * NPT * CH;

    short8 bq0, bq1, bq2, bq3, bq4, bq5;
    {
        const unsigned short* qp = fp + (size_t)tq * 3072 + lane * 8;
        bq0 = *reinterpret_cast<const short8*>(qp);
        bq1 = *reinterpret_cast<const short8*>(qp + 512);
        bq2 = *reinterpret_cast<const short8*>(qp + 1024);
        bq3 = *reinterpret_cast<const short8*>(qp + 1536);
        bq4 = *reinterpret_cast<const short8*>(qp + 2048);
        bq5 = *reinterpret_cast<const short8*>(qp + 2560);
    }

    unsigned int Q[16];
    #pragma unroll
    for (int e = 0; e < 16; ++e) Q[e] = 0xFFFFFFFFu;

    const float* sq = sqv + b * NPT;
    const unsigned short* pa = fp + (size_t)tm0 * 3072 + lane * 8;

    for (int it = 0; it < 32; ++it){
        const unsigned short* p = pa + (size_t)it * 3072;
        short8 a0 = *reinterpret_cast<const short8*>(p);
        short8 a1 = *reinterpret_cast<const short8*>(p + 512);
        short8 a2 = *reinterpret_cast<const short8*>(p + 1024);
        short8 a3 = *reinterpret_cast<const short8*>(p + 1536);
        short8 a4 = *reinterpret_cast<const short8*>(p + 2048);
        short8 a5 = *reinterpret_cast<const short8*>(p + 2560);
        const int tm = tm0 + it;
        float4 s4 = *reinterpret_cast<const float4*>(sq + tm * 16 + 4 * g);

        f32x4 acc = {0.f, 0.f, 0.f, 0.f};
        acc = __builtin_amdgcn_mfma_f32_16x16x32_bf16(a0, bq0, acc, 0, 0, 0);
        acc = __builtin_amdgcn_mfma_f32_16x16x32_bf16(a1, bq1, acc, 0, 0, 0);
        acc = __builtin_amdgcn_mfma_f32_16x16x32_bf16(a2, bq2, acc, 0, 0, 0);
        acc = __builtin_amdgcn_mfma_f32_16x16x32_bf16(a3, bq3, acc, 0, 0, 0);
        acc = __builtin_amdgcn_mfma_f32_16x16x32_bf16(a4, bq4, acc, 0, 0, 0);
        acc = __builtin_amdgcn_mfma_f32_16x16x32_bf16(a5, bq5, acc, 0, 0, 0);

        const int m0 = tm * 16 + 4 * g;
        float sa[4] = {s4.x, s4.y, s4.z, s4.w};
        #pragma unroll
        for (int u = 0; u < 4; ++u){
            float d = fmaxf(fmaf(-2.0f, acc[u], sa[u]), 0.0f);
            unsigned int k = (__builtin_bit_cast(unsigned int, d) & 0xFFFFF000u)
                           | (unsigned int)(m0 + u);
            #pragma unroll
            for (int pz = 0; pz < 8; ++pz){
                unsigned int a = Q[2 * pz], bv = Q[2 * pz + 1];
                Q[2 * pz]     = umin_(a, k);
                Q[2 * pz + 1] = umed3_(a, bv, k);
                k             = umax_(bv, k);
            }
        }
    }

    #pragma unroll 1
    for (int rd = 0; rd < 16; ++rd){
        unsigned int v = Q[0];
        v = umin_(v, (unsigned int)__shfl_xor((int)v, 16));
        v = umin_(v, (unsigned int)__shfl_xor((int)v, 32));
        bool win = (Q[0] == v);
        if (win){
            #pragma unroll
            for (int e = 0; e < 15; ++e) Q[e] = Q[e + 1];
            Q[15] = 0xFFFFFFFFu;
        }
        if (g == 0) mlist[wv][r][rd] = v;
    }
    if (g == 0) mlist[wv][r][16] = 0xFFFFFFFFu;
    __syncthreads();

    if (tid < 64){
        const int qq = tid;
        const int q2 = qq >> 4, rr = qq & 15;
        int i0 = 0, i1 = 0, i2 = 0, i3 = 0;
        int* op = idxh + ((size_t)(b * NPT + qt * 64 + qq) * 2 + half) * KPH;
        for (int rd = 0; rd < KPH; ++rd){
            unsigned int k0 = mlist[q2 * 4 + 0][rr][i0];
            unsigned int k1 = mlist[q2 * 4 + 1][rr][i1];
            unsigned int k2 = mlist[q2 * 4 + 2][rr][i2];
            unsigned int k3 = mlist[q2 * 4 + 3][rr][i3];
            unsigned int mm = umin_(umin_(k0, k1), umin_(k2, k3));
            op[rd] = (int)(mm & 0xFFFu);
            i0 += (k0 == mm); i1 += (k1 == mm); i2 += (k2 == mm); i3 += (k3 == mm);
        }
    }
}

// ---------------- fused refine v4: 2 queries/wave, 32-lane groups, certified f64 fallback -------
__global__ __launch_bounds__(256) void k_refine(
    const float* __restrict__ feat32, const double* __restrict__ featT,
    const int* __restrict__ idxh, int* __restrict__ idxf)
{
    const int q = blockIdx.x * 8 + (threadIdx.x >> 5);
    const int b = blockIdx.y;
    const int sl = threadIdx.x & 31;
    const int* cl = idxh + ((size_t)b * NPT + q) * KCAND;
    const float* qv = feat32 + ((size_t)b * NPT + q) * CH;
    float qr[6];
    #pragma unroll
    for (int j = 0; j < 6; ++j) qr[j] = qv[sl + 32 * j];

    float myd = INFINITY; int mym = 0x7fffffff;
    #pragma unroll
    for (int t0 = 0; t0 < KCAND; t0 += 8){
        float pd[8]; int cm[8];
        #pragma unroll
        for (int j = 0; j < 8; ++j){
            int m = cl[t0 + j];
            cm[j] = m;
            const float* cv = feat32 + ((size_t)b * NPT + m) * CH;
            float d = 0.f;
            #pragma unroll
            for (int e = 0; e < 6; ++e){
                float dv = cv[sl + 32 * e] - qr[e];
                d = fmaf(dv, dv, d);
            }
            pd[j] = d;
        }
        #pragma unroll
        for (int j = 0; j < 8; ++j){
            float d = pd[j];
            #pragma unroll
            for (int off = 16; off; off >>= 1) d += __shfl_xor(d, off, 32);
            if (sl == t0 + j){ myd = d; mym = cm[j]; }
        }
    }

    float d16 = 0.f;
    for (int r = 0; r < KNB; ++r){
        float bv = myd; int bi = mym;
        #pragma unroll
        for (int off = 16; off; off >>= 1){
            float ov = __shfl_xor(bv, off, 32);
            int   oi = __shfl_xor(bi, off, 32);
            if (ov < bv || (ov == bv && oi < bi)){ bv = ov; bi = oi; }
        }
        if (sl == 0) idxf[((size_t)b * NPT + q) * KNB + r] = bi;
        if (mym == bi){ myd = INFINITY; mym = 0x7fffffff; }
        d16 = bv;
    }
    float b17 = myd;
    #pragma unroll
    for (int off = 16; off; off >>= 1) b17 = fminf(b17, __shfl_xor(b17, off, 32));
    int flag = (b17 - d16 < 1e-3f + 2e-4f * d16) ? 1 : 0;
    flag = __shfl(flag, 0, 32);
    if (!flag) return;

    const double* qvd = featT + ((size_t)b * NPT + q) * CH;
    double qrd[6];
    #pragma unroll
    for (int j = 0; j < 6; ++j) qrd[j] = qvd[sl + 32 * j];
    double mydd = INFINITY; int mymd = 0x7fffffff;
    for (int t = 0; t < KCAND; ++t){
        int m = cl[t];
        const double* cv = featT + ((size_t)b * NPT + m) * CH;
        double d = 0.;
        #pragma unroll
        for (int e = 0; e < 6; ++e){
            double dv = cv[sl + 32 * e] - qrd[e];
            d = fma(dv, dv, d);
        }
        #pragma unroll
        for (int off = 16; off; off >>= 1) d += __shfl_xor(d, off, 32);
        if (sl == t){ mydd = d; mymd = m; }
    }
    for (int r = 0; r < KNB; ++r){
        double bv = mydd; int bi = mymd;
        #pragma unroll
        for (int off = 16; off; off >>= 1){
            double ov = __shfl_xor(bv, off, 32);
            int    oi = __shfl_xor(bi, off, 32);
            if (ov < bv || (ov == bv && oi < bi)){ bv = ov; bi = oi; }
        }
        if (sl == 0) idxf[((size_t)b * NPT + q) * KNB + r] = bi;
        if (mymd == bi){ mydd = INFINITY; mymd = 0x7fffffff; }
    }
}

// ---------------- gather v3: coalesced rows, inline BN0 shift, emits bf16 MFMA fragments --------
__global__ __launch_bounds__(128) void k_gather2(
    const float* __restrict__ feat32, const float* __restrict__ g0,
    const float* __restrict__ b0, const double* __restrict__ s0sum,
    const double* __restrict__ s0sq, const int* __restrict__ idx,
    unsigned short* __restrict__ hfrag)
{
    __shared__ float lt[192 * 33];
    __shared__ int il[32 * KNB];
    __shared__ float shl[CH];
    const int tid = threadIdx.x;
    const int n0  = blockIdx.x * 32;
    const int cg  = blockIdx.y;
    const int b   = blockIdx.z;

    for (int i = tid; i < 32 * KNB; i += 128)
        il[i] = idx[((size_t)b * NPT + n0) * KNB + i];
    for (int i = tid; i < CH; i += 128){
        double mean = s0sum[i] / NT64;
        double var  = s0sq[i] / NT64 - mean * mean;
        double sc   = (1.0 / sqrt(var + 1e-5)) * (double)g0[i];
        shl[i] = (float)((double)b0[i] - mean * sc);
    }
    __syncthreads();

    const int nl = tid >> 2, sub = tid & 3;
    const int n  = n0 + nl;
    const float* fbase = feat32 + (size_t)b * NPT * CH;
    const float* qr = fbase + (size_t)n * CH + cg * 96;

    float4 qv[6], mx[6];
    #pragma unroll
    for (int j = 0; j < 6; ++j){
        qv[j] = *reinterpret_cast<const float4*>(qr + (sub + 4 * j) * 4);
        mx[j] = make_float4(-INFINITY, -INFINITY, -INFINITY, -INFINITY);
    }

    #pragma unroll 4
    for (int k = 0; k < KNB; ++k){
        const float* cr = fbase + (size_t)il[nl * KNB + k] * CH + cg * 96;
        #pragma unroll
        for (int j = 0; j < 6; ++j){
            float4 v = *reinterpret_cast<const float4*>(cr + (sub + 4 * j) * 4);
            mx[j].x = fmaxf(mx[j].x, v.x - qv[j].x);
            mx[j].y = fmaxf(mx[j].y, v.y - qv[j].y);
            mx[j].z = fmaxf(mx[j].z, v.z - qv[j].z);
            mx[j].w = fmaxf(mx[j].w, v.w - qv[j].w);
        }
    }

    #pragma unroll
    for (int j = 0; j < 6; ++j){
        const int cb = (sub + 4 * j) * 4;
        float4 s4 = *reinterpret_cast<const float4*>(&shl[cg * 96 + cb]);
        float fi[4] = {qv[j].x + s4.x, qv[j].y + s4.y, qv[j].z + s4.z, qv[j].w + s4.w};
        float mm[4] = {mx[j].x, mx[j].y, mx[j].z, mx[j].w};
        #pragma unroll
        for (int e = 0; e < 4; ++e){
            int cl = cb + e;
            lt[(2 * cl) * 33 + nl]     = fi[e];
            lt[(2 * cl + 1) * 33 + nl] = mm[e];
        }
    }
    __syncthreads();

    const int jt0 = (b * NPT + n0) >> 4;
    const int wvv = tid >> 6;
    const int l   = tid & 63;
    for (int p = wvv; p < 12; p += 2){
        const int t_ = p & 1, ksl = p >> 1;
        short8 pk;
        #pragma unroll
        for (int e = 0; e < 8; ++e){
            int ic = ksl * 32 + (l >> 4) * 8 + e;
            pk[e] = (short)bf16rnd(lt[ic * 33 + t_ * 16 + (l & 15)]);
        }
        *reinterpret_cast<short8*>(
            &hfrag[((size_t)(jt0 + t_) * 12 + cg * 6 + ksl) * 512 + l * 8]) = pk;
    }
}

// ---------------- w_mr -> bf16 MFMA fragments ----------------------------------------------------
__global__ __launch_bounds__(64) void k_wprep(
    const float* __restrict__ wmr, unsigned short* __restrict__ wfrag)
{
    const int ot = blockIdx.x, ks = blockIdx.y, l = threadIdx.x;
    short8 pk;
    #pragma unroll
    for (int e = 0; e < 8; ++e)
        pk[e] = (short)bf16rnd(wmr[(size_t)(ot * 16 + (l & 15)) * (2 * CH) + ks * 32 + (l >> 4) * 8 + e]);
    *reinterpret_cast<short8*>(&wfrag[((size_t)ot * 12 + ks) * 512 + l * 8]) = pk;
}

// ---------------- mr-conv GEMM via MFMA (bf16 fragments), bias + fused BN1 stats ----------------
__global__ __launch_bounds__(256) void k_gemm_mr(
    const unsigned short* __restrict__ hfrag, const unsigned short* __restrict__ wfrag,
    const float* __restrict__ bias, float* __restrict__ out,
    float* __restrict__ s1sum, float* __restrict__ s1sq)
{
    __shared__ unsigned short hl[4 * 12 * 512];
    __shared__ unsigned short wl[12 * 512];
    __shared__ float sstat[2 * CH];
    const int tid = threadIdx.x;
    const int wv = tid >> 6, lane = tid & 63;
    const int g = lane >> 4;
    const int j0 = blockIdx.x * 64;
    const int b  = j0 >> 12;
    const int n0 = j0 & (NPT - 1);

    const unsigned short* hsrc = hfrag + (size_t)(j0 >> 4) * 12 * 512;
    for (int i = tid; i < 3072; i += 256)
        *reinterpret_cast<short8*>(&hl[i * 8]) = *reinterpret_cast<const short8*>(&hsrc[i * 8]);
    for (int i = tid; i < 2 * CH; i += 256) sstat[i] = 0.f;
    __syncthreads();

    for (int ot = 0; ot < 12; ++ot){
        for (int i = tid; i < 768; i += 256)
            *reinterpret_cast<short8*>(&wl[i * 8]) =
                *reinterpret_cast<const short8*>(&wfrag[((size_t)ot * 12) * 512 + i * 8]);
        __syncthreads();

        f32x4 acc = {0.f, 0.f, 0.f, 0.f};
        #pragma unroll
        for (int ks = 0; ks < 12; ++ks){
            short8 a = *reinterpret_cast<const short8*>(&wl[ks * 512 + lane * 8]);
            short8 h = *reinterpret_cast<const short8*>(&hl[(wv * 12 + ks) * 512 + lane * 8]);
            acc = __builtin_amdgcn_mfma_f32_16x16x32_bf16(a, h, acc, 0, 0, 0);
        }

        #pragma unroll
        for (int u = 0; u < 4; ++u){
            const int row = ot * 16 + 4 * g + u;
            float val = acc[u] + bias[row];
            out[((size_t)b * CH + row) * NPT + n0 + wv * 16 + (lane & 15)] = val;
            float s = val, q = val * val;
            #pragma unroll
            for (int off = 1; off < 16; off <<= 1){
                s += __shfl_xor(s, off, 16);
                q += __shfl_xor(q, off, 16);
            }
            if ((lane & 15) == 0){
                atomicAdd(&sstat[row], s);
                atomicAdd(&sstat[CH + row], q);
            }
        }
        __syncthreads();
    }

    if (tid < CH){
        atomicAdd(&s1sum[tid], sstat[tid]);
        atomicAdd(&s1sq[tid],  sstat[CH + tid]);
    }
}

// ---------------- u v2: BN1 + double-gelu -> ufrag (bf16 fragments) + BN2-stat atomics ----------
// grid (NPT/32, BSZ), 256 thr. Block = 32 n x 192 c.
__global__ __launch_bounds__(256) void k_u(
    const float* __restrict__ t2, const float* __restrict__ s1sum, const float* __restrict__ s1sq,
    const float* __restrict__ gm, const float* __restrict__ bm,
    unsigned short* __restrict__ ufrag, float* __restrict__ s2sum, float* __restrict__ s2sq)
{
    __shared__ float lt[CH * 33];
    __shared__ float sstatS[CH], sstatQ[CH];
    __shared__ float scl1[CH], shl1[CH];
    const int tid = threadIdx.x;
    const int n0 = blockIdx.x * 32;
    const int b  = blockIdx.y;
    const float invn = 1.0f / NTOT;
    for (int c = tid; c < CH; c += 256){
        float mean = s1sum[c] * invn;
        float var  = s1sq[c] * invn - mean * mean;
        float rstd = rsqrtf(var + 1e-5f);
        float s = rstd * gm[c];
        scl1[c] = s; shl1[c] = bm[c] - mean * s;
        sstatS[c] = 0.f; sstatQ[c] = 0.f;
    }
    __syncthreads();

    for (int i = tid; i < CH * 32; i += 256){
        int c = i >> 5, nl = i & 31;
        float v = t2[((size_t)b * CH + c) * NPT + n0 + nl];
        float uv = gelu_exact(gelu_exact(fmaf(v, scl1[c], shl1[c])));
        lt[c * 33 + nl] = uv;
        float s = uv, q = uv * uv;
        #pragma unroll
        for (int off = 16; off; off >>= 1){
            s += __shfl_xor(s, off, 32);
            q += __shfl_xor(q, off, 32);
        }
        if ((tid & 31) == 0){
            atomicAdd(&sstatS[c], s);
            atomicAdd(&sstatQ[c], q);
        }
    }
    __syncthreads();

    // emit bf16 fragments: 2 n-subtiles x 6 ks slots
    const int jt0 = (b * NPT + n0) >> 4;
    const int wvv = tid >> 6, l = tid & 63;
    for (int p = wvv; p < 12; p += 4){
        const int t_ = p & 1, ksl = p >> 1;
        short8 pk;
        #pragma unroll
        for (int e = 0; e < 8; ++e){
            int c = ksl * 32 + (l >> 4) * 8 + e;
            pk[e] = (short)bf16rnd(lt[c * 33 + t_ * 16 + (l & 15)]);
        }
        *reinterpret_cast<short8*>(&ufrag[((size_t)(jt0 + t_) * 6 + ksl) * 512 + l * 8]) = pk;
    }

    if (tid < CH){
        atomicAdd(&s2sum[tid], sstatS[tid]);
        atomicAdd(&s2sq[tid],  sstatQ[tid]);
    }
}

// ---------------- w2 * diag(scl2) -> bf16 fragments (BN2 folded into weights) -------------------
__global__ __launch_bounds__(64) void k_w2prep(
    const float* __restrict__ w2, const float* __restrict__ s2sum, const float* __restrict__ s2sq,
    const float* __restrict__ g1, unsigned short* __restrict__ wfrag2)
{
    const int ot = blockIdx.x, ks = blockIdx.y, l = threadIdx.x;
    const float invn = 1.0f / NTOT;
    short8 pk;
    #pragma unroll
    for (int e = 0; e < 8; ++e){
        int c = ks * 32 + (l >> 4) * 8 + e;
        float mean = s2sum[c] * invn;
        float var  = s2sq[c] * invn - mean * mean;
        float scl  = rsqrtf(var + 1e-5f) * g1[c];
        pk[e] = (short)bf16rnd(w2[(size_t)(ot * 16 + (l & 15)) * CH + c] * scl);
    }
    *reinterpret_cast<short8*>(&wfrag2[((size_t)ot * 6 + ks) * 512 + l * 8]) = pk;
}

// ---------------- bias2[o] = sum_c w2[o][c]*shl2[c]  (fp32, exact fold of BN2 shift) ------------
__global__ __launch_bounds__(256) void k_bias2(
    const float* __restrict__ w2, const float* __restrict__ s2sum, const float* __restrict__ s2sq,
    const float* __restrict__ g1, const float* __restrict__ b1, float* __restrict__ bias2)
{
    __shared__ float shl[CH];
    const int tid = threadIdx.x;
    const float invn = 1.0f / NTOT;
    for (int c = tid; c < CH; c += 256){
        float mean = s2sum[c] * invn;
        float var  = s2sq[c] * invn - mean * mean;
        float scl  = rsqrtf(var + 1e-5f) * g1[c];
        shl[c] = b1[c] - mean * scl;
    }
    __syncthreads();
    if (tid < CH){
        float s = 0.f;
        for (int c = 0; c < CH; ++c)
            s = fmaf(w2[(size_t)tid * CH + c], shl[c], s);
        bias2[tid] = s;
    }
}

// ---------------- fc2 via MFMA (bf16 fragments) + bias2 + residual ------------------------------
__global__ __launch_bounds__(256) void k_gemm_fc2(
    const unsigned short* __restrict__ ufrag, const unsigned short* __restrict__ wfrag2,
    const float* __restrict__ bias2, const float* __restrict__ resid, float* __restrict__ out)
{
    __shared__ unsigned short hl[4 * 6 * 512];   // 24 KB
    __shared__ unsigned short wl[6 * 512];       // 6 KB
    const int tid = threadIdx.x;
    const int wv = tid >> 6, lane = tid & 63;
    const int g = lane >> 4;
    const int j0 = blockIdx.x * 64;
    const int b  = j0 >> 12;
    const int n0 = j0 & (NPT - 1);

    const unsigned short* hsrc = ufrag + (size_t)(j0 >> 4) * 6 * 512;
    for (int i = tid; i < 1536; i += 256)
        *reinterpret_cast<short8*>(&hl[i * 8]) = *reinterpret_cast<const short8*>(&hsrc[i * 8]);
    __syncthreads();

    for (int ot = 0; ot < 12; ++ot){
        for (int i = tid; i < 384; i += 256)
            *reinterpret_cast<short8*>(&wl[i * 8]) =
                *reinterpret_cast<const short8*>(&wfrag2[((size_t)ot * 6) * 512 + i * 8]);
        __syncthreads();

        f32x4 acc = {0.f, 0.f, 0.f, 0.f};
        #pragma unroll
        for (int ks = 0; ks < 6; ++ks){
            short8 a = *reinterpret_cast<const short8*>(&wl[ks * 512 + lane * 8]);
            short8 h = *reinterpret_cast<const short8*>(&hl[(wv * 6 + ks) * 512 + lane * 8]);
            acc = __builtin_amdgcn_mfma_f32_16x16x32_bf16(a, h, acc, 0, 0, 0);
        }

        #pragma unroll
        for (int u = 0; u < 4; ++u){
            const int row = ot * 16 + 4 * g + u;
            size_t off = ((size_t)b * CH + row) * NPT + n0 + wv * 16 + (lane & 15);
            out[off] = acc[u] + bias2[row] + resid[off];
        }
        __syncthreads();
    }
}

extern "C" void kernel_launch(void* const* d_in, const int* in_sizes, int n_in,
                              void* d_out, int out_size, void* d_ws, size_t ws_size,
                              hipStream_t stream)
{
    const float* x    = (const float*)d_in[0];
    const float* w1   = (const float*)d_in[1];
    const float* w2   = (const float*)d_in[2];
    const float* wmr  = (const float*)d_in[3];
    const float* bmr  = (const float*)d_in[4];
    const float* g0   = (const float*)d_in[5];
    const float* b0   = (const float*)d_in[6];
    const float* gm   = (const float*)d_in[7];
    const float* bm   = (const float*)d_in[8];
    const float* g1   = (const float*)d_in[9];
    const float* b1   = (const float*)d_in[10];
    float* outp = (float*)d_out;

    const size_t BCN = (size_t)BSZ * CH * NPT;
    float*  A      = (float*)d_ws;                       // BCN f32: t2
    float*  Bb     = A + BCN;                            // BCN f32: featP -> ufrag (bf16)
    unsigned short* featP = (unsigned short*)Bb;
    unsigned short* ufrag = (unsigned short*)Bb;         // featP dead after kNN
    float*  Cc     = Bb + BCN;                           // 2*BCN f32: t1d (f64) -> hfrag (bf16)
    double* t1d    = (double*)Cc;
    unsigned short* hfrag = (unsigned short*)Cc;
    double* featT  = (double*)(Cc + 2 * BCN);            // BCN f64
    float*  feat32 = (float*)(featT + BCN);              // BCN f32
    float*  sqv    = feat32 + BCN;                       // B*N
    int*    idxh   = (int*)(sqv + (size_t)BSZ * NPT);    // B*N*32
    int*    idxf   = idxh + (size_t)BSZ * NPT * KCAND;   // B*N*16
    float*  bnacc  = (float*)(idxf + (size_t)BSZ * NPT * KNB);  // 4*CH f32
    float *s1sum = bnacc, *s1sq = bnacc + CH, *s2sum = bnacc + 2 * CH, *s2sq = bnacc + 3 * CH;
    double* s0sum  = (double*)(bnacc + 4 * CH);          // CH f64
    double* s0sq   = s0sum + CH;                         // CH f64
    unsigned short* wfrag  = (unsigned short*)(s0sq + CH);      // 12*12*512
    unsigned short* wfrag2 = wfrag + 12 * 12 * 512;             // 12*6*512
    float* bias2 = (float*)(wfrag2 + 12 * 6 * 512);             // CH f32

    dim3 gg(NPT / 1024, CH / 8, BSZ);

    hipMemsetAsync(bnacc, 0, 4 * CH * sizeof(float) + 2 * CH * sizeof(double), stream);
    // w_mr -> bf16 fragments (tiny)
    k_wprep<<<dim3(12, 12), 64, 0, stream>>>(wmr, wfrag);
    // fc1 (f64 accumulate) + fused BN0 stats
    k_fc1_f64<<<gg, 256, 0, stream>>>(x, w1, t1d, s0sum, s0sq);
    // fused transpose/scale (inline BN0 scale) -> featT + feat32 + featP + sqv
    k_feat<<<dim3(NPT / 32, BSZ), dim3(32, 8), 0, stream>>>(t1d, g0, s0sum, s0sq,
                                                            featT, feat32, featP, sqv);
    // kNN prefilter v12 (16 waves/block)
    k_knn_mfma<<<dim3(2 * NPT / 64, BSZ), 1024, 0, stream>>>(featP, sqv, idxh);
    // fused refine v4 (certified f64 fallback)
    k_refine<<<dim3(NPT / 8, BSZ), 256, 0, stream>>>(feat32, featT, idxh, idxf);
    // gather v3: inline BN0 shift, emits bf16 fragments (over dead t1d)
    k_gather2<<<dim3(NPT / 32, 2, BSZ), 128, 0, stream>>>(feat32, g0, b0, s0sum, s0sq, idxf, hfrag);
    // mr conv via MFMA + bias + BN1-stat atomics
    k_gemm_mr<<<dim3(BSZ * NPT / 64), 256, 0, stream>>>(hfrag, wfrag, bmr, A, s1sum, s1sq);
    // u v2: BN1 + double-gelu -> ufrag + BN2 stats (ufrag overwrites dead featP)
    k_u<<<dim3(NPT / 32, BSZ), 256, 0, stream>>>(A, s1sum, s1sq, gm, bm, ufrag, s2sum, s2sq);
    // BN2 folded into weights + bias
    k_w2prep<<<dim3(12, 6), 64, 0, stream>>>(w2, s2sum, s2sq, g1, wfrag2);
    k_bias2<<<1, 256, 0, stream>>>(w2, s2sum, s2sq, g1, b1, bias2);
    // fc2 via MFMA + bias2 + residual
    k_gemm_fc2<<<dim3(BSZ * NPT / 64), 256, 0, stream>>>(ufrag, wfrag2, bias2, x, outp);
}